// Round 1
// baseline (15840.669 us; speedup 1.0000x reference)
//
#include <hip/hip_runtime.h>
#include <hip/hip_bf16.h>

#define N_NODES   50000
#define N_EDGES   800000
#define N_TOT     850000   // edges + self loops
#define N_GRAPHS  256
#define HEADS     8
#define NEG_SLOPE 0.2f

__device__ __forceinline__ unsigned ordered(float f) {
    unsigned u = __float_as_uint(f);
    return (u & 0x80000000u) ? ~u : (u | 0x80000000u);
}
__device__ __forceinline__ float unordered(unsigned u) {
    unsigned b = (u & 0x80000000u) ? (u ^ 0x80000000u) : ~u;
    return __uint_as_float(b);
}

// H[n][fout] = sum_k X[n][k] * W[k][fout]
template<int FIN, int FOUT>
__global__ __launch_bounds__(256) void gemm_kernel(const float* __restrict__ X,
                                                   const float* __restrict__ W,
                                                   float* __restrict__ H) {
    const int NPB = 16;                 // nodes per block (50000 / 16 = 3125 exact)
    __shared__ float xs[NPB * (FIN + 1)];
    const int tid = threadIdx.x;
    const int node0 = blockIdx.x * NPB;
    for (int i = tid; i < NPB * FIN; i += 256) {
        int nn = i / FIN, kk = i % FIN;
        xs[nn * (FIN + 1) + kk] = X[(node0 + nn) * FIN + kk];
    }
    __syncthreads();
    const int NCOPY = 256 / FOUT;       // 4 (FOUT=64) or 2 (FOUT=128)
    const int NPT = NPB / NCOPY;        // 4 or 8 nodes per thread
    const int fout = tid & (FOUT - 1);
    const int copy = tid / FOUT;
    float acc[NPT];
#pragma unroll
    for (int j = 0; j < NPT; ++j) acc[j] = 0.f;
    for (int k = 0; k < FIN; ++k) {
        float w = W[k * FOUT + fout];
#pragma unroll
        for (int j = 0; j < NPT; ++j)
            acc[j] += xs[(copy + j * NCOPY) * (FIN + 1) + k] * w;
    }
#pragma unroll
    for (int j = 0; j < NPT; ++j)
        H[(node0 + copy + j * NCOPY) * FOUT + fout] = acc[j];
}

// asrc[n][h] = sum_c H[n][h][c]*a_src[h][c];  same for adst
template<int CH>
__global__ void alpha_kernel(const float* __restrict__ H,
                             const float* __restrict__ a_src,
                             const float* __restrict__ a_dst,
                             float* __restrict__ asrc, float* __restrict__ adst) {
    int tid = blockIdx.x * blockDim.x + threadIdx.x;
    if (tid >= N_NODES * HEADS) return;
    int n = tid / HEADS, h = tid % HEADS;
    const float* hp = H + n * (HEADS * CH) + h * CH;
    float s = 0.f, d = 0.f;
#pragma unroll
    for (int c = 0; c < CH; ++c) {
        float v = hp[c];
        s += v * a_src[h * CH + c];
        d += v * a_dst[h * CH + c];
    }
    asrc[tid] = s;
    adst[tid] = d;
}

__global__ void maxlogit_kernel(const int* __restrict__ esrc, const int* __restrict__ edst,
                                const float* __restrict__ asrc, const float* __restrict__ adst,
                                unsigned* __restrict__ m_u) {
    int e = blockIdx.x * blockDim.x + threadIdx.x;
    if (e >= N_TOT) return;
    int s, d;
    if (e < N_EDGES) { s = esrc[e]; d = edst[e]; } else { s = d = e - N_EDGES; }
    const float4* sp = (const float4*)(asrc + s * 8);
    const float4* dp = (const float4*)(adst + d * 8);
    float4 s0 = sp[0], s1 = sp[1], d0 = dp[0], d1 = dp[1];
    float ls[8] = {s0.x + d0.x, s0.y + d0.y, s0.z + d0.z, s0.w + d0.w,
                   s1.x + d1.x, s1.y + d1.y, s1.z + d1.z, s1.w + d1.w};
#pragma unroll
    for (int h = 0; h < 8; ++h) {
        float l = ls[h];
        l = l > 0.f ? l : NEG_SLOPE * l;
        atomicMax(&m_u[d * 8 + h], ordered(l));
    }
}

__global__ void denom_kernel(const int* __restrict__ esrc, const int* __restrict__ edst,
                             const float* __restrict__ asrc, const float* __restrict__ adst,
                             const unsigned* __restrict__ m_u, float* __restrict__ denom) {
    int e = blockIdx.x * blockDim.x + threadIdx.x;
    if (e >= N_TOT) return;
    int s, d;
    if (e < N_EDGES) { s = esrc[e]; d = edst[e]; } else { s = d = e - N_EDGES; }
    const float4* sp = (const float4*)(asrc + s * 8);
    const float4* dp = (const float4*)(adst + d * 8);
    float4 s0 = sp[0], s1 = sp[1], d0 = dp[0], d1 = dp[1];
    float ls[8] = {s0.x + d0.x, s0.y + d0.y, s0.z + d0.z, s0.w + d0.w,
                   s1.x + d1.x, s1.y + d1.y, s1.z + d1.z, s1.w + d1.w};
#pragma unroll
    for (int h = 0; h < 8; ++h) {
        float l = ls[h];
        l = l > 0.f ? l : NEG_SLOPE * l;
        float mf = unordered(m_u[d * 8 + h]);
        atomicAdd(&denom[d * 8 + h], expf(l - mf));
    }
}

template<int CH>
__global__ void msg_kernel(const int* __restrict__ esrc, const int* __restrict__ edst,
                           const float* __restrict__ asrc, const float* __restrict__ adst,
                           const unsigned* __restrict__ m_u, const float* __restrict__ denom,
                           const float* __restrict__ H, float* __restrict__ out) {
    int tid = blockIdx.x * blockDim.x + threadIdx.x;
    if (tid >= N_TOT * HEADS) return;
    int e = tid / HEADS, h = tid % HEADS;
    int s, d;
    if (e < N_EDGES) { s = esrc[e]; d = edst[e]; } else { s = d = e - N_EDGES; }
    float l = asrc[s * 8 + h] + adst[d * 8 + h];
    l = l > 0.f ? l : NEG_SLOPE * l;
    float mf = unordered(m_u[d * 8 + h]);
    float ev = expf(l - mf);
    float alpha = ev / (denom[d * 8 + h] + 1e-16f);
    const float* hp = H + s * (HEADS * CH) + h * CH;
    float* op = out + d * (HEADS * CH) + h * CH;
#pragma unroll
    for (int c = 0; c < CH; c += 4) {
        float4 hv = *(const float4*)(hp + c);
        atomicAdd(op + c + 0, hv.x * alpha);
        atomicAdd(op + c + 1, hv.y * alpha);
        atomicAdd(op + c + 2, hv.z * alpha);
        atomicAdd(op + c + 3, hv.w * alpha);
    }
}

template<int F>
__global__ void bias_elu_kernel(float* __restrict__ acc, const float* __restrict__ bias) {
    int tid = blockIdx.x * blockDim.x + threadIdx.x;
    if (tid >= N_NODES * F) return;
    float v = acc[tid] + bias[tid & (F - 1)];
    acc[tid] = v > 0.f ? v : expm1f(v);
}

__global__ void pool_kernel(const float* __restrict__ act, const int* __restrict__ batch,
                            float* __restrict__ pooled, float* __restrict__ pcount) {
    int tid = blockIdx.x * blockDim.x + threadIdx.x;
    if (tid >= N_NODES * 128) return;
    int n = tid >> 7, f = tid & 127;
    int g = batch[n];
    atomicAdd(&pooled[g * 128 + f], act[tid]);
    if (f == 0) atomicAdd(&pcount[g], 1.0f);
}

__global__ void head_kernel(const float* __restrict__ pooled, const float* __restrict__ pcount,
                            const float* __restrict__ fc1_w, const float* __restrict__ fc1_b,
                            const float* __restrict__ fc2_w, const float* __restrict__ fc2_b,
                            float* __restrict__ out) {
    __shared__ float sm[128];
    __shared__ float zz[10];
    int g = blockIdx.x, t = threadIdx.x;
    float cnt = pcount[g];
    cnt = cnt > 1.f ? cnt : 1.f;
    sm[t] = pooled[g * 128 + t] / cnt;
    __syncthreads();
    if (t < 10) {
        float z = fc1_b[t];
        for (int f = 0; f < 128; ++f) z += sm[f] * fc1_w[f * 10 + t];
        zz[t] = z > 0.f ? z : 0.f;
    }
    __syncthreads();
    if (t == 0) {
        float o = fc2_b[0];
#pragma unroll
        for (int j = 0; j < 10; ++j) o += zz[j] * fc2_w[j];
        out[g] = o;
    }
}

extern "C" void kernel_launch(void* const* d_in, const int* in_sizes, int n_in,
                              void* d_out, int out_size, void* d_ws, size_t ws_size,
                              hipStream_t stream) {
    const float* x      = (const float*)d_in[0];
    const float* W1     = (const float*)d_in[1];
    const float* a_src1 = (const float*)d_in[2];
    const float* a_dst1 = (const float*)d_in[3];
    const float* b1     = (const float*)d_in[4];
    const float* W2     = (const float*)d_in[5];
    const float* a_src2 = (const float*)d_in[6];
    const float* a_dst2 = (const float*)d_in[7];
    const float* b2     = (const float*)d_in[8];
    const float* W3     = (const float*)d_in[9];
    const float* a_src3 = (const float*)d_in[10];
    const float* a_dst3 = (const float*)d_in[11];
    const float* b3     = (const float*)d_in[12];
    const float* fc1_w  = (const float*)d_in[13];
    const float* fc1_b  = (const float*)d_in[14];
    const float* fc2_w  = (const float*)d_in[15];
    const float* fc2_b  = (const float*)d_in[16];
    const int*   eidx   = (const int*)d_in[17];
    const int*   batch  = (const int*)d_in[18];
    const int* esrc = eidx;
    const int* edst = eidx + N_EDGES;
    float* out = (float*)d_out;

    float* ws     = (float*)d_ws;
    float* h_buf  = ws;                       // 50000*128 = 6,400,000 f32
    float* act0   = h_buf + 6400000;          // 6,400,000
    float* act1   = act0 + 6400000;           // 6,400,000
    float* asrcb  = act1 + 6400000;           // 400,000
    float* adstb  = asrcb + 400000;           // 400,000
    unsigned* m_u = (unsigned*)(adstb + 400000); // 400,000
    float* denom  = (float*)(m_u + 400000);   // 400,000
    float* pooled = denom + 400000;           // 32,768
    float* pcount = pooled + 32768;           // 256

    const int B = 256;
    dim3 blk(B);
    dim3 g_gemm(N_NODES / 16);
    dim3 g_alpha((N_NODES * HEADS + B - 1) / B);
    dim3 g_edge((N_TOT + B - 1) / B);
    dim3 g_eh((N_TOT * HEADS + B - 1) / B);

    // ---- Layer 1: Fin=32, F=64, CH=8 ----
    hipMemsetAsync(m_u, 0, 400000 * 4, stream);
    hipMemsetAsync(denom, 0, 400000 * 4, stream);
    hipMemsetAsync(act0, 0, (size_t)N_NODES * 64 * 4, stream);
    gemm_kernel<32, 64><<<g_gemm, blk, 0, stream>>>(x, W1, h_buf);
    alpha_kernel<8><<<g_alpha, blk, 0, stream>>>(h_buf, a_src1, a_dst1, asrcb, adstb);
    maxlogit_kernel<<<g_edge, blk, 0, stream>>>(esrc, edst, asrcb, adstb, m_u);
    denom_kernel<<<g_edge, blk, 0, stream>>>(esrc, edst, asrcb, adstb, m_u, denom);
    msg_kernel<8><<<g_eh, blk, 0, stream>>>(esrc, edst, asrcb, adstb, m_u, denom, h_buf, act0);
    bias_elu_kernel<64><<<dim3((N_NODES * 64 + B - 1) / B), blk, 0, stream>>>(act0, b1);

    // ---- Layer 2: Fin=64, F=128, CH=16 ----
    hipMemsetAsync(m_u, 0, 400000 * 4, stream);
    hipMemsetAsync(denom, 0, 400000 * 4, stream);
    hipMemsetAsync(act1, 0, (size_t)N_NODES * 128 * 4, stream);
    gemm_kernel<64, 128><<<g_gemm, blk, 0, stream>>>(act0, W2, h_buf);
    alpha_kernel<16><<<g_alpha, blk, 0, stream>>>(h_buf, a_src2, a_dst2, asrcb, adstb);
    maxlogit_kernel<<<g_edge, blk, 0, stream>>>(esrc, edst, asrcb, adstb, m_u);
    denom_kernel<<<g_edge, blk, 0, stream>>>(esrc, edst, asrcb, adstb, m_u, denom);
    msg_kernel<16><<<g_eh, blk, 0, stream>>>(esrc, edst, asrcb, adstb, m_u, denom, h_buf, act1);
    bias_elu_kernel<128><<<dim3((N_NODES * 128 + B - 1) / B), blk, 0, stream>>>(act1, b2);

    // ---- Layer 3: Fin=128, F=128, CH=16 ----
    hipMemsetAsync(m_u, 0, 400000 * 4, stream);
    hipMemsetAsync(denom, 0, 400000 * 4, stream);
    hipMemsetAsync(act0, 0, (size_t)N_NODES * 128 * 4, stream);
    gemm_kernel<128, 128><<<g_gemm, blk, 0, stream>>>(act1, W3, h_buf);
    alpha_kernel<16><<<g_alpha, blk, 0, stream>>>(h_buf, a_src3, a_dst3, asrcb, adstb);
    maxlogit_kernel<<<g_edge, blk, 0, stream>>>(esrc, edst, asrcb, adstb, m_u);
    denom_kernel<<<g_edge, blk, 0, stream>>>(esrc, edst, asrcb, adstb, m_u, denom);
    msg_kernel<16><<<g_eh, blk, 0, stream>>>(esrc, edst, asrcb, adstb, m_u, denom, h_buf, act0);
    bias_elu_kernel<128><<<dim3((N_NODES * 128 + B - 1) / B), blk, 0, stream>>>(act0, b3);

    // ---- Pool + head ----
    hipMemsetAsync(pooled, 0, (32768 + 256) * 4, stream);
    pool_kernel<<<dim3((N_NODES * 128 + B - 1) / B), blk, 0, stream>>>(act0, batch, pooled, pcount);
    head_kernel<<<dim3(N_GRAPHS), dim3(128), 0, stream>>>(pooled, pcount, fc1_w, fc1_b,
                                                          fc2_w, fc2_b, out);
}

// Round 3
// 730.513 us; speedup vs baseline: 21.6843x; 21.6843x over previous
//
#include <hip/hip_runtime.h>
#include <hip/hip_bf16.h>

#define N_NODES   50000
#define N_EDGES   800000
#define N_TOT     850000   // edges + self loops
#define N_GRAPHS  256
#define HEADS     8
#define NEG_SLOPE 0.2f

// ---------------- dense GEMM: H[n][fout] = sum_k X[n][k]*W[k][fout] ----------
template<int FIN, int FOUT>
__global__ __launch_bounds__(256) void gemm_kernel(const float* __restrict__ X,
                                                   const float* __restrict__ W,
                                                   float* __restrict__ H) {
    const int NPB = 16;                 // nodes per block (50000/16 = 3125 exact)
    __shared__ float xs[NPB * (FIN + 1)];
    const int tid = threadIdx.x;
    const int node0 = blockIdx.x * NPB;
    for (int i = tid; i < NPB * FIN; i += 256) {
        int nn = i / FIN, kk = i % FIN;
        xs[nn * (FIN + 1) + kk] = X[(node0 + nn) * FIN + kk];
    }
    __syncthreads();
    const int NCOPY = 256 / FOUT;
    const int NPT = NPB / NCOPY;
    const int fout = tid & (FOUT - 1);
    const int copy = tid / FOUT;
    float acc[NPT];
#pragma unroll
    for (int j = 0; j < NPT; ++j) acc[j] = 0.f;
    for (int k = 0; k < FIN; ++k) {
        float w = W[k * FOUT + fout];
#pragma unroll
        for (int j = 0; j < NPT; ++j)
            acc[j] += xs[(copy + j * NCOPY) * (FIN + 1) + k] * w;
    }
#pragma unroll
    for (int j = 0; j < NPT; ++j)
        H[(node0 + copy + j * NCOPY) * FOUT + fout] = acc[j];
}

// --------- asrc[n][h] = sum_c H[n][h][c]*a_src[h][c]; same for adst ---------
template<int CH>
__global__ void alpha_kernel(const float* __restrict__ H,
                             const float* __restrict__ a_src,
                             const float* __restrict__ a_dst,
                             float* __restrict__ asrc, float* __restrict__ adst) {
    int tid = blockIdx.x * blockDim.x + threadIdx.x;
    if (tid >= N_NODES * HEADS) return;
    int n = tid / HEADS, h = tid % HEADS;
    const float* hp = H + n * (HEADS * CH) + h * CH;
    float s = 0.f, d = 0.f;
#pragma unroll
    for (int c = 0; c < CH; ++c) {
        float v = hp[c];
        s += v * a_src[h * CH + c];
        d += v * a_dst[h * CH + c];
    }
    asrc[tid] = s;
    adst[tid] = d;
}

// ---------------- CSR build (counting sort by dst) --------------------------
__global__ void hist_kernel(const int* __restrict__ edst, int* __restrict__ cnt) {
    int e = blockIdx.x * blockDim.x + threadIdx.x;
    if (e >= N_TOT) return;
    int d = (e < N_EDGES) ? edst[e] : e - N_EDGES;
    atomicAdd(&cnt[d], 1);
}

__global__ void scan1_kernel(const int* __restrict__ cnt, int* __restrict__ excl,
                             int* __restrict__ bsum) {
    __shared__ int sm[256];
    int t = threadIdx.x;
    int i = blockIdx.x * 256 + t;
    int v = (i < N_NODES) ? cnt[i] : 0;
    sm[t] = v;
    __syncthreads();
    for (int off = 1; off < 256; off <<= 1) {
        int x = (t >= off) ? sm[t - off] : 0;
        __syncthreads();
        sm[t] += x;
        __syncthreads();
    }
    if (i < N_NODES) excl[i] = sm[t] - v;
    if (t == 255) bsum[blockIdx.x] = sm[255];
}

__global__ void scan2_kernel(int* __restrict__ bsum, int nblk) {
    __shared__ int sm[256];
    int t = threadIdx.x;
    int v = (t < nblk) ? bsum[t] : 0;
    sm[t] = v;
    __syncthreads();
    for (int off = 1; off < 256; off <<= 1) {
        int x = (t >= off) ? sm[t - off] : 0;
        __syncthreads();
        sm[t] += x;
        __syncthreads();
    }
    if (t < nblk) bsum[t] = sm[t] - v;   // exclusive
}

__global__ void scan3_kernel(const int* __restrict__ excl, const int* __restrict__ bsum,
                             int* __restrict__ row_ptr) {
    int i = blockIdx.x * blockDim.x + threadIdx.x;
    if (i < N_NODES) row_ptr[i] = excl[i] + bsum[i >> 8];
    if (i == N_NODES) row_ptr[N_NODES] = N_TOT;
}

__global__ void scatter_kernel(const int* __restrict__ esrc, const int* __restrict__ edst,
                               const int* __restrict__ row_ptr, int* __restrict__ cursor,
                               int* __restrict__ edge_src) {
    int e = blockIdx.x * blockDim.x + threadIdx.x;
    if (e >= N_TOT) return;
    int s, d;
    if (e < N_EDGES) { s = esrc[e]; d = edst[e]; } else { s = d = e - N_EDGES; }
    int pos = row_ptr[d] + atomicAdd(&cursor[d], 1);
    edge_src[pos] = s;
}

// ------- fused gather: online softmax + aggregation + bias + ELU ------------
// one wave (64 lanes) per destination node; lane = h*8 + cl; CPL = CH/8 chans/lane
template<int CH>
__global__ __launch_bounds__(256) void gat_gather_kernel(
        const int* __restrict__ row_ptr, const int* __restrict__ edge_src,
        const float* __restrict__ asrc, const float* __restrict__ adst,
        const float* __restrict__ H, const float* __restrict__ bias,
        float* __restrict__ out) {
    const int n = (blockIdx.x * blockDim.x + threadIdx.x) >> 6;
    if (n >= N_NODES) return;
    const int lane = threadIdx.x & 63;
    const int CPL = CH / 8;
    const int h = lane >> 3;
    const int c0 = (lane & 7) * CPL;
    const float adst_h = adst[n * 8 + h];
    const int e0 = row_ptr[n], e1 = row_ptr[n + 1];
    float m = -1e38f, sum = 0.f;
    float acc[CPL];
#pragma unroll
    for (int j = 0; j < CPL; ++j) acc[j] = 0.f;
    for (int e = e0; e < e1; ++e) {
        int s = edge_src[e];
        float l = asrc[s * 8 + h] + adst_h;
        l = l > 0.f ? l : NEG_SLOPE * l;
        float mnew = fmaxf(m, l);
        float r = __expf(m - mnew);      // 1 when m unchanged, 0 first iter
        float w = __expf(l - mnew);
        sum = sum * r + w;
        const float* hp = H + s * (8 * CH) + h * CH + c0;
#pragma unroll
        for (int j = 0; j < CPL; ++j) acc[j] = acc[j] * r + w * hp[j];
        m = mnew;
    }
    float inv = 1.0f / (sum + 1e-16f);
    float* op = out + n * (8 * CH) + h * CH + c0;
    const float* bp = bias + h * CH + c0;
#pragma unroll
    for (int j = 0; j < CPL; ++j) {
        float v = acc[j] * inv + bp[j];
        op[j] = v > 0.f ? v : expm1f(v);
    }
}

// ---------------- pool + head -----------------------------------------------
__global__ void pool_kernel(const float* __restrict__ act, const int* __restrict__ batch,
                            float* __restrict__ pooled, float* __restrict__ pcount) {
    int tid = blockIdx.x * blockDim.x + threadIdx.x;
    if (tid >= N_NODES * 128) return;
    int n = tid >> 7, f = tid & 127;
    int g = batch[n];
    atomicAdd(&pooled[g * 128 + f], act[tid]);
    if (f == 0) atomicAdd(&pcount[g], 1.0f);
}

__global__ void head_kernel(const float* __restrict__ pooled, const float* __restrict__ pcount,
                            const float* __restrict__ fc1_w, const float* __restrict__ fc1_b,
                            const float* __restrict__ fc2_w, const float* __restrict__ fc2_b,
                            float* __restrict__ out) {
    __shared__ float sm[128];
    __shared__ float zz[10];
    int g = blockIdx.x, t = threadIdx.x;
    float cnt = pcount[g];
    cnt = cnt > 1.f ? cnt : 1.f;
    sm[t] = pooled[g * 128 + t] / cnt;
    __syncthreads();
    if (t < 10) {
        float z = fc1_b[t];
        for (int f = 0; f < 128; ++f) z += sm[f] * fc1_w[f * 10 + t];
        zz[t] = z > 0.f ? z : 0.f;
    }
    __syncthreads();
    if (t == 0) {
        float o = fc2_b[0];
#pragma unroll
        for (int j = 0; j < 10; ++j) o += zz[j] * fc2_w[j];
        out[g] = o;
    }
}

extern "C" void kernel_launch(void* const* d_in, const int* in_sizes, int n_in,
                              void* d_out, int out_size, void* d_ws, size_t ws_size,
                              hipStream_t stream) {
    const float* x      = (const float*)d_in[0];
    const float* W1     = (const float*)d_in[1];
    const float* a_src1 = (const float*)d_in[2];
    const float* a_dst1 = (const float*)d_in[3];
    const float* b1     = (const float*)d_in[4];
    const float* W2     = (const float*)d_in[5];
    const float* a_src2 = (const float*)d_in[6];
    const float* a_dst2 = (const float*)d_in[7];
    const float* b2     = (const float*)d_in[8];
    const float* W3     = (const float*)d_in[9];
    const float* a_src3 = (const float*)d_in[10];
    const float* a_dst3 = (const float*)d_in[11];
    const float* b3     = (const float*)d_in[12];
    const float* fc1_w  = (const float*)d_in[13];
    const float* fc1_b  = (const float*)d_in[14];
    const float* fc2_w  = (const float*)d_in[15];
    const float* fc2_b  = (const float*)d_in[16];
    const int*   eidx   = (const int*)d_in[17];
    const int*   batch  = (const int*)d_in[18];
    const int* esrc = eidx;
    const int* edst = eidx + N_EDGES;
    float* out = (float*)d_out;

    float* ws      = (float*)d_ws;
    float* h_buf   = ws;                         // 6,400,000 f32
    float* act0    = h_buf + 6400000;            // 6,400,000
    float* act1    = act0 + 6400000;             // 6,400,000
    float* asrcb   = act1 + 6400000;             // 400,000
    float* adstb   = asrcb + 400000;             // 400,000
    int*   cnt     = (int*)(adstb + 400000);     // 50,000
    int*   excl    = cnt + 50000;                // 50,000
    int*   bsum    = excl + 50000;               // 256
    int*   row_ptr = bsum + 256;                 // 50,001
    int*   cursor  = row_ptr + 50001;            // 50,000
    int*   edge_src= cursor + 50000;             // 850,000
    float* pooled  = (float*)(edge_src + 850000);// 32,768
    float* pcount  = pooled + 32768;             // 256

    const int B = 256;
    dim3 blk(B);
    dim3 g_gemm(N_NODES / 16);
    dim3 g_alpha((N_NODES * HEADS + B - 1) / B);
    dim3 g_edge((N_TOT + B - 1) / B);
    dim3 g_gather((N_NODES * 64 + B - 1) / B);
    const int nblk_scan = (N_NODES + 255) / 256;   // 196

    // ---- build CSR (once per call, reused by all 3 layers) ----
    hipMemsetAsync(cnt, 0, 50000 * 4, stream);
    hipMemsetAsync(cursor, 0, 50000 * 4, stream);
    hist_kernel<<<g_edge, blk, 0, stream>>>(edst, cnt);
    scan1_kernel<<<dim3(nblk_scan), blk, 0, stream>>>(cnt, excl, bsum);
    scan2_kernel<<<dim3(1), blk, 0, stream>>>(bsum, nblk_scan);
    scan3_kernel<<<dim3((N_NODES + B) / B), blk, 0, stream>>>(excl, bsum, row_ptr);
    scatter_kernel<<<g_edge, blk, 0, stream>>>(esrc, edst, row_ptr, cursor, edge_src);

    // ---- Layer 1: Fin=32, F=64, CH=8 ----
    gemm_kernel<32, 64><<<g_gemm, blk, 0, stream>>>(x, W1, h_buf);
    alpha_kernel<8><<<g_alpha, blk, 0, stream>>>(h_buf, a_src1, a_dst1, asrcb, adstb);
    gat_gather_kernel<8><<<g_gather, blk, 0, stream>>>(row_ptr, edge_src, asrcb, adstb,
                                                       h_buf, b1, act0);

    // ---- Layer 2: Fin=64, F=128, CH=16 ----
    gemm_kernel<64, 128><<<g_gemm, blk, 0, stream>>>(act0, W2, h_buf);
    alpha_kernel<16><<<g_alpha, blk, 0, stream>>>(h_buf, a_src2, a_dst2, asrcb, adstb);
    gat_gather_kernel<16><<<g_gather, blk, 0, stream>>>(row_ptr, edge_src, asrcb, adstb,
                                                        h_buf, b2, act1);

    // ---- Layer 3: Fin=128, F=128, CH=16 ----
    gemm_kernel<128, 128><<<g_gemm, blk, 0, stream>>>(act1, W3, h_buf);
    alpha_kernel<16><<<g_alpha, blk, 0, stream>>>(h_buf, a_src3, a_dst3, asrcb, adstb);
    gat_gather_kernel<16><<<g_gather, blk, 0, stream>>>(row_ptr, edge_src, asrcb, adstb,
                                                        h_buf, b3, act0);

    // ---- Pool + head ----
    hipMemsetAsync(pooled, 0, (32768 + 256) * 4, stream);
    pool_kernel<<<dim3((N_NODES * 128 + B - 1) / B), blk, 0, stream>>>(act0, batch, pooled, pcount);
    head_kernel<<<dim3(N_GRAPHS), dim3(128), 0, stream>>>(pooled, pcount, fc1_w, fc1_b,
                                                          fc2_w, fc2_b, out);
}

// Round 4
// 589.099 us; speedup vs baseline: 26.8896x; 1.2400x over previous
//
#include <hip/hip_runtime.h>
#include <hip/hip_bf16.h>

#define N_NODES   50000
#define N_EDGES   800000
#define N_TOT     850000   // edges + self loops
#define N_GRAPHS  256
#define HEADS     8
#define NEG_SLOPE 0.2f

// ---------------- dense GEMM: H[n][fout] = sum_k X[n][k]*W[k][fout] ----------
template<int FIN, int FOUT>
__global__ __launch_bounds__(256) void gemm_kernel(const float* __restrict__ X,
                                                   const float* __restrict__ W,
                                                   float* __restrict__ H) {
    const int NPB = 16;                 // nodes per block (50000/16 = 3125 exact)
    __shared__ float xs[NPB * (FIN + 1)];
    const int tid = threadIdx.x;
    const int node0 = blockIdx.x * NPB;
    for (int i = tid; i < NPB * FIN; i += 256) {
        int nn = i / FIN, kk = i % FIN;
        xs[nn * (FIN + 1) + kk] = X[(node0 + nn) * FIN + kk];
    }
    __syncthreads();
    const int NCOPY = 256 / FOUT;
    const int NPT = NPB / NCOPY;
    const int fout = tid & (FOUT - 1);
    const int copy = tid / FOUT;
    float acc[NPT];
#pragma unroll
    for (int j = 0; j < NPT; ++j) acc[j] = 0.f;
    for (int k = 0; k < FIN; ++k) {
        float w = W[k * FOUT + fout];
#pragma unroll
        for (int j = 0; j < NPT; ++j)
            acc[j] += xs[(copy + j * NCOPY) * (FIN + 1) + k] * w;
    }
#pragma unroll
    for (int j = 0; j < NPT; ++j)
        H[(node0 + copy + j * NCOPY) * FOUT + fout] = acc[j];
}

// --------- asrc[n][h] = sum_c H[n][h][c]*a_src[h][c]; same for adst ---------
template<int CH>
__global__ void alpha_kernel(const float* __restrict__ H,
                             const float* __restrict__ a_src,
                             const float* __restrict__ a_dst,
                             float* __restrict__ asrc, float* __restrict__ adst) {
    int tid = blockIdx.x * blockDim.x + threadIdx.x;
    if (tid >= N_NODES * HEADS) return;
    int n = tid / HEADS, h = tid % HEADS;
    const float* hp = H + n * (HEADS * CH) + h * CH;
    float s = 0.f, d = 0.f;
#pragma unroll
    for (int c = 0; c < CH; ++c) {
        float v = hp[c];
        s += v * a_src[h * CH + c];
        d += v * a_dst[h * CH + c];
    }
    asrc[tid] = s;
    adst[tid] = d;
}

// ---------------- CSR build (counting sort by dst) --------------------------
__global__ void hist_kernel(const int* __restrict__ edst, int* __restrict__ cnt) {
    int e = blockIdx.x * blockDim.x + threadIdx.x;
    if (e >= N_TOT) return;
    int d = (e < N_EDGES) ? edst[e] : e - N_EDGES;
    atomicAdd(&cnt[d], 1);
}

__global__ void scan1_kernel(const int* __restrict__ cnt, int* __restrict__ excl,
                             int* __restrict__ bsum) {
    __shared__ int sm[256];
    int t = threadIdx.x;
    int i = blockIdx.x * 256 + t;
    int v = (i < N_NODES) ? cnt[i] : 0;
    sm[t] = v;
    __syncthreads();
    for (int off = 1; off < 256; off <<= 1) {
        int x = (t >= off) ? sm[t - off] : 0;
        __syncthreads();
        sm[t] += x;
        __syncthreads();
    }
    if (i < N_NODES) excl[i] = sm[t] - v;
    if (t == 255) bsum[blockIdx.x] = sm[255];
}

__global__ void scan2_kernel(int* __restrict__ bsum, int nblk) {
    __shared__ int sm[256];
    int t = threadIdx.x;
    int v = (t < nblk) ? bsum[t] : 0;
    sm[t] = v;
    __syncthreads();
    for (int off = 1; off < 256; off <<= 1) {
        int x = (t >= off) ? sm[t - off] : 0;
        __syncthreads();
        sm[t] += x;
        __syncthreads();
    }
    if (t < nblk) bsum[t] = sm[t] - v;   // exclusive
}

__global__ void scan3_kernel(const int* __restrict__ excl, const int* __restrict__ bsum,
                             int* __restrict__ row_ptr) {
    int i = blockIdx.x * blockDim.x + threadIdx.x;
    if (i < N_NODES) row_ptr[i] = excl[i] + bsum[i >> 8];
    if (i == N_NODES) row_ptr[N_NODES] = N_TOT;
}

__global__ void scatter_kernel(const int* __restrict__ esrc, const int* __restrict__ edst,
                               const int* __restrict__ row_ptr, int* __restrict__ cursor,
                               int* __restrict__ edge_src) {
    int e = blockIdx.x * blockDim.x + threadIdx.x;
    if (e >= N_TOT) return;
    int s, d;
    if (e < N_EDGES) { s = esrc[e]; d = edst[e]; } else { s = d = e - N_EDGES; }
    int pos = row_ptr[d] + atomicAdd(&cursor[d], 1);
    edge_src[pos] = s;
}

// ------- fused gather: online softmax + aggregation + bias + ELU ------------
// one wave (64 lanes) per destination node; lane = h*8 + cl; CPL = CH/8 chans/lane
template<int CH>
__global__ __launch_bounds__(256) void gat_gather_kernel(
        const int* __restrict__ row_ptr, const int* __restrict__ edge_src,
        const float* __restrict__ asrc, const float* __restrict__ adst,
        const float* __restrict__ H, const float* __restrict__ bias,
        float* __restrict__ out) {
    const int n = (blockIdx.x * blockDim.x + threadIdx.x) >> 6;
    if (n >= N_NODES) return;
    const int lane = threadIdx.x & 63;
    const int CPL = CH / 8;
    const int h = lane >> 3;
    const int c0 = (lane & 7) * CPL;
    const float adst_h = adst[n * 8 + h];
    const int e0 = row_ptr[n], e1 = row_ptr[n + 1];
    float m = -1e38f, sum = 0.f;
    float acc[CPL];
#pragma unroll
    for (int j = 0; j < CPL; ++j) acc[j] = 0.f;
    for (int e = e0; e < e1; ++e) {
        int s = edge_src[e];
        float l = asrc[s * 8 + h] + adst_h;
        l = l > 0.f ? l : NEG_SLOPE * l;
        float mnew = fmaxf(m, l);
        float r = __expf(m - mnew);      // 1 when m unchanged, 0 first iter
        float w = __expf(l - mnew);
        sum = sum * r + w;
        const float* hp = H + s * (8 * CH) + h * CH + c0;
#pragma unroll
        for (int j = 0; j < CPL; ++j) acc[j] = acc[j] * r + w * hp[j];
        m = mnew;
    }
    float inv = 1.0f / (sum + 1e-16f);
    float* op = out + n * (8 * CH) + h * CH + c0;
    const float* bp = bias + h * CH + c0;
#pragma unroll
    for (int j = 0; j < CPL; ++j) {
        float v = acc[j] * inv + bp[j];
        op[j] = v > 0.f ? v : expm1f(v);
    }
}

// ---------------- pool + head (sorted batch -> no atomics) ------------------
__global__ void gstart_kernel(const int* __restrict__ batch, int* __restrict__ gstart) {
    int g = threadIdx.x;                 // one block of 256
    int lo = 0, hi = N_NODES;
    while (lo < hi) {                    // lower_bound(batch, g)
        int mid = (lo + hi) >> 1;
        if (batch[mid] < g) lo = mid + 1; else hi = mid;
    }
    gstart[g] = lo;
    if (g == 0) gstart[N_GRAPHS] = N_NODES;
}

__global__ __launch_bounds__(128) void pool_head_kernel(
        const float* __restrict__ act, const int* __restrict__ gstart,
        const float* __restrict__ fc1_w, const float* __restrict__ fc1_b,
        const float* __restrict__ fc2_w, const float* __restrict__ fc2_b,
        float* __restrict__ out) {
    int g = blockIdx.x, t = threadIdx.x;  // 128 threads, feature t
    int n0 = gstart[g], n1 = gstart[g + 1];
    float s = 0.f;
    for (int n = n0; n < n1; ++n) s += act[n * 128 + t];
    float cnt = (float)(n1 - n0);
    cnt = cnt > 1.f ? cnt : 1.f;
    __shared__ float sm[128];
    __shared__ float zz[10];
    sm[t] = s / cnt;
    __syncthreads();
    if (t < 10) {
        float z = fc1_b[t];
        for (int f = 0; f < 128; ++f) z += sm[f] * fc1_w[f * 10 + t];
        zz[t] = z > 0.f ? z : 0.f;
    }
    __syncthreads();
    if (t == 0) {
        float o = fc2_b[0];
#pragma unroll
        for (int j = 0; j < 10; ++j) o += zz[j] * fc2_w[j];
        out[g] = o;
    }
}

extern "C" void kernel_launch(void* const* d_in, const int* in_sizes, int n_in,
                              void* d_out, int out_size, void* d_ws, size_t ws_size,
                              hipStream_t stream) {
    const float* x      = (const float*)d_in[0];
    const float* W1     = (const float*)d_in[1];
    const float* a_src1 = (const float*)d_in[2];
    const float* a_dst1 = (const float*)d_in[3];
    const float* b1     = (const float*)d_in[4];
    const float* W2     = (const float*)d_in[5];
    const float* a_src2 = (const float*)d_in[6];
    const float* a_dst2 = (const float*)d_in[7];
    const float* b2     = (const float*)d_in[8];
    const float* W3     = (const float*)d_in[9];
    const float* a_src3 = (const float*)d_in[10];
    const float* a_dst3 = (const float*)d_in[11];
    const float* b3     = (const float*)d_in[12];
    const float* fc1_w  = (const float*)d_in[13];
    const float* fc1_b  = (const float*)d_in[14];
    const float* fc2_w  = (const float*)d_in[15];
    const float* fc2_b  = (const float*)d_in[16];
    const int*   eidx   = (const int*)d_in[17];
    const int*   batch  = (const int*)d_in[18];
    const int* esrc = eidx;
    const int* edst = eidx + N_EDGES;
    float* out = (float*)d_out;

    float* ws      = (float*)d_ws;
    float* h_buf   = ws;                         // 6,400,000 f32
    float* act0    = h_buf + 6400000;            // 6,400,000
    float* act1    = act0 + 6400000;             // 6,400,000
    float* asrcb   = act1 + 6400000;             // 400,000
    float* adstb   = asrcb + 400000;             // 400,000
    int*   cnt     = (int*)(adstb + 400000);     // 50,000
    int*   excl    = cnt + 50000;                // 50,000
    int*   bsum    = excl + 50000;               // 256
    int*   row_ptr = bsum + 256;                 // 50,001
    int*   cursor  = row_ptr + 50001;            // 50,000
    int*   edge_src= cursor + 50000;             // 850,000
    int*   gstart  = edge_src + 850000;          // 257

    const int B = 256;
    dim3 blk(B);
    dim3 g_gemm(N_NODES / 16);
    dim3 g_alpha((N_NODES * HEADS + B - 1) / B);
    dim3 g_edge((N_TOT + B - 1) / B);
    dim3 g_gather((N_NODES * 64 + B - 1) / B);
    const int nblk_scan = (N_NODES + 255) / 256;   // 196

    // ---- build CSR (once per call, reused by all 3 layers) ----
    hipMemsetAsync(cnt, 0, 50000 * 4, stream);
    hipMemsetAsync(cursor, 0, 50000 * 4, stream);
    hist_kernel<<<g_edge, blk, 0, stream>>>(edst, cnt);
    scan1_kernel<<<dim3(nblk_scan), blk, 0, stream>>>(cnt, excl, bsum);
    scan2_kernel<<<dim3(1), blk, 0, stream>>>(bsum, nblk_scan);
    scan3_kernel<<<dim3((N_NODES + B) / B), blk, 0, stream>>>(excl, bsum, row_ptr);
    scatter_kernel<<<g_edge, blk, 0, stream>>>(esrc, edst, row_ptr, cursor, edge_src);
    gstart_kernel<<<dim3(1), blk, 0, stream>>>(batch, gstart);

    // ---- Layer 1: Fin=32, F=64, CH=8 ----
    gemm_kernel<32, 64><<<g_gemm, blk, 0, stream>>>(x, W1, h_buf);
    alpha_kernel<8><<<g_alpha, blk, 0, stream>>>(h_buf, a_src1, a_dst1, asrcb, adstb);
    gat_gather_kernel<8><<<g_gather, blk, 0, stream>>>(row_ptr, edge_src, asrcb, adstb,
                                                       h_buf, b1, act0);

    // ---- Layer 2: Fin=64, F=128, CH=16 ----
    gemm_kernel<64, 128><<<g_gemm, blk, 0, stream>>>(act0, W2, h_buf);
    alpha_kernel<16><<<g_alpha, blk, 0, stream>>>(h_buf, a_src2, a_dst2, asrcb, adstb);
    gat_gather_kernel<16><<<g_gather, blk, 0, stream>>>(row_ptr, edge_src, asrcb, adstb,
                                                        h_buf, b2, act1);

    // ---- Layer 3: Fin=128, F=128, CH=16 ----
    gemm_kernel<128, 128><<<g_gemm, blk, 0, stream>>>(act1, W3, h_buf);
    alpha_kernel<16><<<g_alpha, blk, 0, stream>>>(h_buf, a_src3, a_dst3, asrcb, adstb);
    gat_gather_kernel<16><<<g_gather, blk, 0, stream>>>(row_ptr, edge_src, asrcb, adstb,
                                                        h_buf, b3, act0);

    // ---- Pool + head (no atomics) ----
    pool_head_kernel<<<dim3(N_GRAPHS), dim3(128), 0, stream>>>(act0, gstart, fc1_w, fc1_b,
                                                               fc2_w, fc2_b, out);
}

// Round 6
// 427.303 us; speedup vs baseline: 37.0713x; 1.3786x over previous
//
#include <hip/hip_runtime.h>
#include <hip/hip_bf16.h>

#define N_NODES   50000
#define N_EDGES   800000
#define N_TOT     850000   // edges + self loops
#define N_GRAPHS  256
#define HEADS     8
#define NEG_SLOPE 0.2f

// ---------------- dense GEMM: H[n][fout] = sum_k X[n][k]*W[k][fout] ----------
// 64-node tile, KC=32 k-chunks staged in LDS (X transposed), all b128 reads.
template<int FIN, int FOUT>
__global__ __launch_bounds__(256) void gemm_kernel(const float* __restrict__ X,
                                                   const float* __restrict__ W,
                                                   float* __restrict__ H) {
    constexpr int KC    = 32;
    constexpr int THR_F = FOUT / 4;        // threads spanning fout (32 or 16)
    constexpr int NPT   = 64 / (256 / THR_F); // nodes per thread (8 or 4)
    constexpr int XS_S  = 68;              // padded node-stride (16B aligned)
    __shared__ float xs[KC * XS_S];        // [k][node]
    __shared__ float ws[KC * FOUT];        // [k][fout]
    const int t = threadIdx.x;
    const int node0 = blockIdx.x * 64;
    const int fo  = (t % THR_F) * 4;
    const int ndb = (t / THR_F) * NPT;
    float4 acc[NPT];
#pragma unroll
    for (int i = 0; i < NPT; ++i) acc[i] = make_float4(0.f, 0.f, 0.f, 0.f);

    const int xn = t >> 2, ks = (t & 3) * 8;   // staging roles
    for (int kc = 0; kc < FIN; kc += KC) {
        __syncthreads();
        // stage X chunk transposed: xs[k][node]
        float4 a0 = make_float4(0.f,0.f,0.f,0.f), a1 = a0;
        if (node0 + xn < N_NODES) {
            const float* xp = X + (size_t)(node0 + xn) * FIN + kc + ks;
            a0 = *(const float4*)xp;
            a1 = *(const float4*)(xp + 4);
        }
        xs[(ks + 0) * XS_S + xn] = a0.x;
        xs[(ks + 1) * XS_S + xn] = a0.y;
        xs[(ks + 2) * XS_S + xn] = a0.z;
        xs[(ks + 3) * XS_S + xn] = a0.w;
        xs[(ks + 4) * XS_S + xn] = a1.x;
        xs[(ks + 5) * XS_S + xn] = a1.y;
        xs[(ks + 6) * XS_S + xn] = a1.z;
        xs[(ks + 7) * XS_S + xn] = a1.w;
        // stage W chunk (row-major, flat float4 copy)
        constexpr int WF4 = KC * FOUT / 4 / 256;   // float4 per thread (4 or 2)
        const float4* wsrc = (const float4*)(W + (size_t)kc * FOUT);
        float4* wdst = (float4*)ws;
#pragma unroll
        for (int i = 0; i < WF4; ++i) wdst[t * WF4 + i] = wsrc[t * WF4 + i];
        __syncthreads();
#pragma unroll 4
        for (int k = 0; k < KC; ++k) {
            float4 wv = *(const float4*)(ws + k * FOUT + fo);
#pragma unroll
            for (int q = 0; q < NPT / 4; ++q) {
                float4 xv = *(const float4*)(xs + k * XS_S + ndb + q * 4);
                acc[q*4+0].x += xv.x * wv.x; acc[q*4+0].y += xv.x * wv.y;
                acc[q*4+0].z += xv.x * wv.z; acc[q*4+0].w += xv.x * wv.w;
                acc[q*4+1].x += xv.y * wv.x; acc[q*4+1].y += xv.y * wv.y;
                acc[q*4+1].z += xv.y * wv.z; acc[q*4+1].w += xv.y * wv.w;
                acc[q*4+2].x += xv.z * wv.x; acc[q*4+2].y += xv.z * wv.y;
                acc[q*4+2].z += xv.z * wv.z; acc[q*4+2].w += xv.z * wv.w;
                acc[q*4+3].x += xv.w * wv.x; acc[q*4+3].y += xv.w * wv.y;
                acc[q*4+3].z += xv.w * wv.z; acc[q*4+3].w += xv.w * wv.w;
            }
        }
    }
#pragma unroll
    for (int i = 0; i < NPT; ++i) {
        int row = node0 + ndb + i;
        if (row < N_NODES) *(float4*)(H + (size_t)row * FOUT + fo) = acc[i];
    }
}

// --------- asrc[n][h] = sum_c H[n][h][c]*a_src[h][c]; same for adst ---------
template<int CH>
__global__ void alpha_kernel(const float* __restrict__ H,
                             const float* __restrict__ a_src,
                             const float* __restrict__ a_dst,
                             float* __restrict__ asrc, float* __restrict__ adst) {
    int tid = blockIdx.x * blockDim.x + threadIdx.x;
    if (tid >= N_NODES * HEADS) return;
    int n = tid / HEADS, h = tid % HEADS;
    const float* hp = H + (size_t)n * (HEADS * CH) + h * CH;
    float s = 0.f, d = 0.f;
#pragma unroll
    for (int c = 0; c < CH; ++c) {
        float v = hp[c];
        s += v * a_src[h * CH + c];
        d += v * a_dst[h * CH + c];
    }
    asrc[tid] = s;
    adst[tid] = d;
}

// ---------------- CSR build (counting sort by dst) --------------------------
__global__ void hist_kernel(const int* __restrict__ edst, int* __restrict__ cnt) {
    int e = blockIdx.x * blockDim.x + threadIdx.x;
    if (e >= N_TOT) return;
    int d = (e < N_EDGES) ? edst[e] : e - N_EDGES;
    atomicAdd(&cnt[d], 1);
}

__global__ void scan1_kernel(const int* __restrict__ cnt, int* __restrict__ excl,
                             int* __restrict__ bsum) {
    __shared__ int sm[256];
    int t = threadIdx.x;
    int i = blockIdx.x * 256 + t;
    int v = (i < N_NODES) ? cnt[i] : 0;
    sm[t] = v;
    __syncthreads();
    for (int off = 1; off < 256; off <<= 1) {
        int x = (t >= off) ? sm[t - off] : 0;
        __syncthreads();
        sm[t] += x;
        __syncthreads();
    }
    if (i < N_NODES) excl[i] = sm[t] - v;
    if (t == 255) bsum[blockIdx.x] = sm[255];
}

__global__ void scan2_kernel(int* __restrict__ bsum, int nblk) {
    __shared__ int sm[256];
    int t = threadIdx.x;
    int v = (t < nblk) ? bsum[t] : 0;
    sm[t] = v;
    __syncthreads();
    for (int off = 1; off < 256; off <<= 1) {
        int x = (t >= off) ? sm[t - off] : 0;
        __syncthreads();
        sm[t] += x;
        __syncthreads();
    }
    if (t < nblk) bsum[t] = sm[t] - v;   // exclusive
}

__global__ void scan3_kernel(const int* __restrict__ excl, const int* __restrict__ bsum,
                             int* __restrict__ row_ptr) {
    int i = blockIdx.x * blockDim.x + threadIdx.x;
    if (i < N_NODES) row_ptr[i] = excl[i] + bsum[i >> 8];
    if (i == N_NODES) row_ptr[N_NODES] = N_TOT;
}

__global__ void scatter_kernel(const int* __restrict__ esrc, const int* __restrict__ edst,
                               const int* __restrict__ row_ptr, int* __restrict__ cursor,
                               int* __restrict__ edge_src) {
    int e = blockIdx.x * blockDim.x + threadIdx.x;
    if (e >= N_TOT) return;
    int s, d;
    if (e < N_EDGES) { s = esrc[e]; d = edst[e]; } else { s = d = e - N_EDGES; }
    int pos = row_ptr[d] + atomicAdd(&cursor[d], 1);
    edge_src[pos] = s;
}

// ------- fused gather: online softmax + aggregation + bias + ELU ------------
// one wave per destination node; LPE = 2*CH lanes per edge (float4 over row),
// SPLIT = 64/LPE edges in flight; flash-merge of sub-accumulators at the end.
template<int CH>
__global__ __launch_bounds__(256) void gat_gather_kernel(
        const int* __restrict__ row_ptr, const int* __restrict__ edge_src,
        const float* __restrict__ asrc, const float* __restrict__ adst,
        const float* __restrict__ H, const float* __restrict__ bias,
        float* __restrict__ out) {
    constexpr int LPE   = 2 * CH;    // 32 (CH16) or 16 (CH8)
    constexpr int SPLIT = 64 / LPE;  // 2 or 4
    constexpr int LPH   = CH / 4;    // lanes per head (4 or 2)
    const int n = (blockIdx.x * blockDim.x + threadIdx.x) >> 6;
    if (n >= N_NODES) return;
    const int lane = threadIdx.x & 63;
    const int sub = lane / LPE;
    const int li  = lane & (LPE - 1);
    const int h   = li / LPH;
    const int off = h * CH + (li & (LPH - 1)) * 4;   // float offset in row
    const float adst_h = adst[n * 8 + h];
    const int e0 = row_ptr[n], e1 = row_ptr[n + 1];
    float m = -1e38f, sum = 0.f;
    float4 acc = make_float4(0.f, 0.f, 0.f, 0.f);
    for (int e = e0 + sub; e < e1; e += SPLIT) {
        int s = edge_src[e];
        float l = asrc[s * 8 + h] + adst_h;
        l = l > 0.f ? l : NEG_SLOPE * l;
        float mnew = fmaxf(m, l);
        float r = __expf(m - mnew);
        float w = __expf(l - mnew);
        sum = sum * r + w;
        float4 hv = *(const float4*)(H + (size_t)s * (8 * CH) + off);
        acc.x = acc.x * r + w * hv.x;
        acc.y = acc.y * r + w * hv.y;
        acc.z = acc.z * r + w * hv.z;
        acc.w = acc.w * r + w * hv.w;
        m = mnew;
    }
    // merge SPLIT sub-accumulators (flash merge)
#pragma unroll
    for (int mask = LPE; mask < 64; mask <<= 1) {
        float m2 = __shfl_xor(m, mask, 64);
        float s2 = __shfl_xor(sum, mask, 64);
        float ax = __shfl_xor(acc.x, mask, 64);
        float ay = __shfl_xor(acc.y, mask, 64);
        float az = __shfl_xor(acc.z, mask, 64);
        float aw = __shfl_xor(acc.w, mask, 64);
        float mm = fmaxf(m, m2);
        float f1 = __expf(m - mm), f2 = __expf(m2 - mm);
        sum = sum * f1 + s2 * f2;
        acc.x = acc.x * f1 + ax * f2;
        acc.y = acc.y * f1 + ay * f2;
        acc.z = acc.z * f1 + az * f2;
        acc.w = acc.w * f1 + aw * f2;
        m = mm;
    }
    float inv = 1.0f / (sum + 1e-16f);
    float4 bv = *(const float4*)(bias + off);
    float4 v;
    v.x = acc.x * inv + bv.x;  v.x = v.x > 0.f ? v.x : expm1f(v.x);
    v.y = acc.y * inv + bv.y;  v.y = v.y > 0.f ? v.y : expm1f(v.y);
    v.z = acc.z * inv + bv.z;  v.z = v.z > 0.f ? v.z : expm1f(v.z);
    v.w = acc.w * inv + bv.w;  v.w = v.w > 0.f ? v.w : expm1f(v.w);
    *(float4*)(out + (size_t)n * (8 * CH) + off) = v;
}

// ---------------- pool + head (sorted batch -> no atomics) ------------------
__global__ void gstart_kernel(const int* __restrict__ batch, int* __restrict__ gstart) {
    int g = threadIdx.x;                 // one block of 256
    int lo = 0, hi = N_NODES;
    while (lo < hi) {                    // lower_bound(batch, g)
        int mid = (lo + hi) >> 1;
        if (batch[mid] < g) lo = mid + 1; else hi = mid;
    }
    gstart[g] = lo;
    if (g == 0) gstart[N_GRAPHS] = N_NODES;
}

__global__ __launch_bounds__(128) void pool_head_kernel(
        const float* __restrict__ act, const int* __restrict__ gstart,
        const float* __restrict__ fc1_w, const float* __restrict__ fc1_b,
        const float* __restrict__ fc2_w, const float* __restrict__ fc2_b,
        float* __restrict__ out) {
    int g = blockIdx.x, t = threadIdx.x;  // 128 threads, feature t
    int n0 = gstart[g], n1 = gstart[g + 1];
    float s = 0.f;
    for (int n = n0; n < n1; ++n) s += act[(size_t)n * 128 + t];
    float cnt = (float)(n1 - n0);
    cnt = cnt > 1.f ? cnt : 1.f;
    __shared__ float sm[128];
    __shared__ float zz[10];
    sm[t] = s / cnt;
    __syncthreads();
    if (t < 10) {
        float z = fc1_b[t];
        for (int f = 0; f < 128; ++f) z += sm[f] * fc1_w[f * 10 + t];
        zz[t] = z > 0.f ? z : 0.f;
    }
    __syncthreads();
    if (t == 0) {
        float o = fc2_b[0];
#pragma unroll
        for (int j = 0; j < 10; ++j) o += zz[j] * fc2_w[j];
        out[g] = o;
    }
}

extern "C" void kernel_launch(void* const* d_in, const int* in_sizes, int n_in,
                              void* d_out, int out_size, void* d_ws, size_t ws_size,
                              hipStream_t stream) {
    const float* x      = (const float*)d_in[0];
    const float* W1     = (const float*)d_in[1];
    const float* a_src1 = (const float*)d_in[2];
    const float* a_dst1 = (const float*)d_in[3];
    const float* b1     = (const float*)d_in[4];
    const float* W2     = (const float*)d_in[5];
    const float* a_src2 = (const float*)d_in[6];
    const float* a_dst2 = (const float*)d_in[7];
    const float* b2     = (const float*)d_in[8];
    const float* W3     = (const float*)d_in[9];
    const float* a_src3 = (const float*)d_in[10];
    const float* a_dst3 = (const float*)d_in[11];
    const float* b3     = (const float*)d_in[12];
    const float* fc1_w  = (const float*)d_in[13];
    const float* fc1_b  = (const float*)d_in[14];
    const float* fc2_w  = (const float*)d_in[15];
    const float* fc2_b  = (const float*)d_in[16];
    const int*   eidx   = (const int*)d_in[17];
    const int*   batch  = (const int*)d_in[18];
    const int* esrc = eidx;
    const int* edst = eidx + N_EDGES;
    float* out = (float*)d_out;

    float* ws      = (float*)d_ws;
    float* h_buf   = ws;                         // 6,400,000 f32
    float* act0    = h_buf + 6400000;            // 6,400,000
    float* act1    = act0 + 6400000;             // 6,400,000
    float* asrcb   = act1 + 6400000;             // 400,000
    float* adstb   = asrcb + 400000;             // 400,000
    int*   cnt     = (int*)(adstb + 400000);     // 50,000
    int*   excl    = cnt + 50000;                // 50,000
    int*   bsum    = excl + 50000;               // 256
    int*   row_ptr = bsum + 256;                 // 50,001
    int*   cursor  = row_ptr + 50001;            // 50,000
    int*   edge_src= cursor + 50000;             // 850,000
    int*   gstart  = edge_src + 850000;          // 257

    const int B = 256;
    dim3 blk(B);
    dim3 g_gemm((N_NODES + 63) / 64);
    dim3 g_alpha((N_NODES * HEADS + B - 1) / B);
    dim3 g_edge((N_TOT + B - 1) / B);
    dim3 g_gather((N_NODES * 64 + B - 1) / B);
    const int nblk_scan = (N_NODES + 255) / 256;   // 196

    // ---- build CSR (once per call, reused by all 3 layers) ----
    hipMemsetAsync(cnt, 0, 50000 * 4, stream);
    hipMemsetAsync(cursor, 0, 50000 * 4, stream);
    hist_kernel<<<g_edge, blk, 0, stream>>>(edst, cnt);
    scan1_kernel<<<dim3(nblk_scan), blk, 0, stream>>>(cnt, excl, bsum);
    scan2_kernel<<<dim3(1), blk, 0, stream>>>(bsum, nblk_scan);
    scan3_kernel<<<dim3((N_NODES + B) / B), blk, 0, stream>>>(excl, bsum, row_ptr);
    scatter_kernel<<<g_edge, blk, 0, stream>>>(esrc, edst, row_ptr, cursor, edge_src);
    gstart_kernel<<<dim3(1), blk, 0, stream>>>(batch, gstart);

    // ---- Layer 1: Fin=32, F=64, CH=8 ----
    gemm_kernel<32, 64><<<g_gemm, blk, 0, stream>>>(x, W1, h_buf);
    alpha_kernel<8><<<g_alpha, blk, 0, stream>>>(h_buf, a_src1, a_dst1, asrcb, adstb);
    gat_gather_kernel<8><<<g_gather, blk, 0, stream>>>(row_ptr, edge_src, asrcb, adstb,
                                                       h_buf, b1, act0);

    // ---- Layer 2: Fin=64, F=128, CH=16 ----
    gemm_kernel<64, 128><<<g_gemm, blk, 0, stream>>>(act0, W2, h_buf);
    alpha_kernel<16><<<g_alpha, blk, 0, stream>>>(h_buf, a_src2, a_dst2, asrcb, adstb);
    gat_gather_kernel<16><<<g_gather, blk, 0, stream>>>(row_ptr, edge_src, asrcb, adstb,
                                                        h_buf, b2, act1);

    // ---- Layer 3: Fin=128, F=128, CH=16 ----
    gemm_kernel<128, 128><<<g_gemm, blk, 0, stream>>>(act1, W3, h_buf);
    alpha_kernel<16><<<g_alpha, blk, 0, stream>>>(h_buf, a_src3, a_dst3, asrcb, adstb);
    gat_gather_kernel<16><<<g_gather, blk, 0, stream>>>(row_ptr, edge_src, asrcb, adstb,
                                                        h_buf, b3, act0);

    // ---- Pool + head (no atomics) ----
    pool_head_kernel<<<dim3(N_GRAPHS), dim3(128), 0, stream>>>(act0, gstart, fc1_w, fc1_b,
                                                               fc2_w, fc2_b, out);
}

// Round 7
// 383.125 us; speedup vs baseline: 41.3459x; 1.1153x over previous
//
#include <hip/hip_runtime.h>
#include <hip/hip_bf16.h>

#define N_NODES   50000
#define N_EDGES   800000
#define N_TOT     850000   // edges + self loops
#define N_GRAPHS  256
#define HEADS     8
#define NEG_SLOPE 0.2f

// ---------------- dense GEMM: H[n][fout] = sum_k X[n][k]*W[k][fout] ----------
// 64-node tile, KC=32 k-chunks staged in LDS (X transposed), all b128 reads.
template<int FIN, int FOUT>
__global__ __launch_bounds__(256) void gemm_kernel(const float* __restrict__ X,
                                                   const float* __restrict__ W,
                                                   float* __restrict__ H) {
    constexpr int KC    = 32;
    constexpr int THR_F = FOUT / 4;        // threads spanning fout (32 or 16)
    constexpr int NPT   = 64 / (256 / THR_F); // nodes per thread (8 or 4)
    constexpr int XS_S  = 68;              // padded node-stride (16B aligned)
    __shared__ float xs[KC * XS_S];        // [k][node]
    __shared__ float ws[KC * FOUT];        // [k][fout]
    const int t = threadIdx.x;
    const int node0 = blockIdx.x * 64;
    const int fo  = (t % THR_F) * 4;
    const int ndb = (t / THR_F) * NPT;
    float4 acc[NPT];
#pragma unroll
    for (int i = 0; i < NPT; ++i) acc[i] = make_float4(0.f, 0.f, 0.f, 0.f);

    const int xn = t >> 2, ks = (t & 3) * 8;   // staging roles
    for (int kc = 0; kc < FIN; kc += KC) {
        __syncthreads();
        // stage X chunk transposed: xs[k][node]
        float4 a0 = make_float4(0.f,0.f,0.f,0.f), a1 = a0;
        if (node0 + xn < N_NODES) {
            const float* xp = X + (size_t)(node0 + xn) * FIN + kc + ks;
            a0 = *(const float4*)xp;
            a1 = *(const float4*)(xp + 4);
        }
        xs[(ks + 0) * XS_S + xn] = a0.x;
        xs[(ks + 1) * XS_S + xn] = a0.y;
        xs[(ks + 2) * XS_S + xn] = a0.z;
        xs[(ks + 3) * XS_S + xn] = a0.w;
        xs[(ks + 4) * XS_S + xn] = a1.x;
        xs[(ks + 5) * XS_S + xn] = a1.y;
        xs[(ks + 6) * XS_S + xn] = a1.z;
        xs[(ks + 7) * XS_S + xn] = a1.w;
        // stage W chunk (row-major, flat float4 copy)
        constexpr int WF4 = KC * FOUT / 4 / 256;   // float4 per thread (4 or 2)
        const float4* wsrc = (const float4*)(W + (size_t)kc * FOUT);
        float4* wdst = (float4*)ws;
#pragma unroll
        for (int i = 0; i < WF4; ++i) wdst[t * WF4 + i] = wsrc[t * WF4 + i];
        __syncthreads();
#pragma unroll 4
        for (int k = 0; k < KC; ++k) {
            float4 wv = *(const float4*)(ws + k * FOUT + fo);
#pragma unroll
            for (int q = 0; q < NPT / 4; ++q) {
                float4 xv = *(const float4*)(xs + k * XS_S + ndb + q * 4);
                acc[q*4+0].x += xv.x * wv.x; acc[q*4+0].y += xv.x * wv.y;
                acc[q*4+0].z += xv.x * wv.z; acc[q*4+0].w += xv.x * wv.w;
                acc[q*4+1].x += xv.y * wv.x; acc[q*4+1].y += xv.y * wv.y;
                acc[q*4+1].z += xv.y * wv.z; acc[q*4+1].w += xv.y * wv.w;
                acc[q*4+2].x += xv.z * wv.x; acc[q*4+2].y += xv.z * wv.y;
                acc[q*4+2].z += xv.z * wv.z; acc[q*4+2].w += xv.z * wv.w;
                acc[q*4+3].x += xv.w * wv.x; acc[q*4+3].y += xv.w * wv.y;
                acc[q*4+3].z += xv.w * wv.z; acc[q*4+3].w += xv.w * wv.w;
            }
        }
    }
#pragma unroll
    for (int i = 0; i < NPT; ++i) {
        int row = node0 + ndb + i;
        if (row < N_NODES) *(float4*)(H + (size_t)row * FOUT + fo) = acc[i];
    }
}

// --------- asrc[n][h] = sum_c H[n][h][c]*a_src[h][c]; same for adst ---------
template<int CH>
__global__ void alpha_kernel(const float* __restrict__ H,
                             const float* __restrict__ a_src,
                             const float* __restrict__ a_dst,
                             float* __restrict__ asrc, float* __restrict__ adst) {
    int tid = blockIdx.x * blockDim.x + threadIdx.x;
    if (tid >= N_NODES * HEADS) return;
    int n = tid / HEADS, h = tid % HEADS;
    const float* hp = H + (size_t)n * (HEADS * CH) + h * CH;
    float s = 0.f, d = 0.f;
#pragma unroll
    for (int c = 0; c < CH; ++c) {
        float v = hp[c];
        s += v * a_src[h * CH + c];
        d += v * a_dst[h * CH + c];
    }
    asrc[tid] = s;
    adst[tid] = d;
}

// ---------------- CSR build (counting sort by dst) --------------------------
__global__ void hist_kernel(const int* __restrict__ edst, int* __restrict__ cnt) {
    int e = blockIdx.x * blockDim.x + threadIdx.x;
    if (e >= N_TOT) return;
    int d = (e < N_EDGES) ? edst[e] : e - N_EDGES;
    atomicAdd(&cnt[d], 1);
}

__global__ void scan1_kernel(const int* __restrict__ cnt, int* __restrict__ excl,
                             int* __restrict__ bsum) {
    __shared__ int sm[256];
    int t = threadIdx.x;
    int i = blockIdx.x * 256 + t;
    int v = (i < N_NODES) ? cnt[i] : 0;
    sm[t] = v;
    __syncthreads();
    for (int off = 1; off < 256; off <<= 1) {
        int x = (t >= off) ? sm[t - off] : 0;
        __syncthreads();
        sm[t] += x;
        __syncthreads();
    }
    if (i < N_NODES) excl[i] = sm[t] - v;
    if (t == 255) bsum[blockIdx.x] = sm[255];
}

__global__ void scan2_kernel(int* __restrict__ bsum, int nblk) {
    __shared__ int sm[256];
    int t = threadIdx.x;
    int v = (t < nblk) ? bsum[t] : 0;
    sm[t] = v;
    __syncthreads();
    for (int off = 1; off < 256; off <<= 1) {
        int x = (t >= off) ? sm[t - off] : 0;
        __syncthreads();
        sm[t] += x;
        __syncthreads();
    }
    if (t < nblk) bsum[t] = sm[t] - v;   // exclusive
}

__global__ void scan3_kernel(const int* __restrict__ excl, const int* __restrict__ bsum,
                             int* __restrict__ row_ptr) {
    int i = blockIdx.x * blockDim.x + threadIdx.x;
    if (i < N_NODES) row_ptr[i] = excl[i] + bsum[i >> 8];
    if (i == N_NODES) row_ptr[N_NODES] = N_TOT;
}

__global__ void scatter_kernel(const int* __restrict__ esrc, const int* __restrict__ edst,
                               const int* __restrict__ row_ptr, int* __restrict__ cursor,
                               int* __restrict__ edge_src) {
    int e = blockIdx.x * blockDim.x + threadIdx.x;
    if (e >= N_TOT) return;
    int s, d;
    if (e < N_EDGES) { s = esrc[e]; d = edst[e]; } else { s = d = e - N_EDGES; }
    int pos = row_ptr[d] + atomicAdd(&cursor[d], 1);
    edge_src[pos] = s;
}

// ------- fused gather: softmax (no max-shift; logits O(1), f32-safe) --------
// one wave per destination node; LPE = 2*CH lanes per edge (float4 over row),
// SPLIT = 64/LPE edges in flight; plain-add merge of sub-accumulators.
template<int CH>
__global__ __launch_bounds__(256) void gat_gather_kernel(
        const int* __restrict__ row_ptr, const int* __restrict__ edge_src,
        const float* __restrict__ asrc, const float* __restrict__ adst,
        const float* __restrict__ H, const float* __restrict__ bias,
        float* __restrict__ out) {
    constexpr int LPE   = 2 * CH;    // 32 (CH16) or 16 (CH8)
    constexpr int SPLIT = 64 / LPE;  // 2 or 4
    constexpr int LPH   = CH / 4;    // lanes per head (4 or 2)
    const int n = (blockIdx.x * blockDim.x + threadIdx.x) >> 6;
    if (n >= N_NODES) return;
    const int lane = threadIdx.x & 63;
    const int sub = lane / LPE;
    const int li  = lane & (LPE - 1);
    const int h   = li / LPH;
    const int off = h * CH + (li & (LPH - 1)) * 4;   // float offset in row
    const float adst_h = adst[n * 8 + h];
    const int e0 = row_ptr[n], e1 = row_ptr[n + 1];
    float sum = 0.f;
    float4 acc = make_float4(0.f, 0.f, 0.f, 0.f);
    for (int e = e0 + sub; e < e1; e += SPLIT) {
        int s = edge_src[e];
        float l = asrc[s * 8 + h] + adst_h;
        l = l > 0.f ? l : NEG_SLOPE * l;
        float w = __expf(l);             // no max-shift: |l| small, f32-safe
        sum += w;
        float4 hv = *(const float4*)(H + (size_t)s * (8 * CH) + off);
        acc.x += w * hv.x;
        acc.y += w * hv.y;
        acc.z += w * hv.z;
        acc.w += w * hv.w;
    }
    // merge SPLIT sub-accumulators (plain adds — same implicit shift of 0)
#pragma unroll
    for (int mask = LPE; mask < 64; mask <<= 1) {
        sum   += __shfl_xor(sum, mask, 64);
        acc.x += __shfl_xor(acc.x, mask, 64);
        acc.y += __shfl_xor(acc.y, mask, 64);
        acc.z += __shfl_xor(acc.z, mask, 64);
        acc.w += __shfl_xor(acc.w, mask, 64);
    }
    float inv = 1.0f / (sum + 1e-16f);
    float4 bv = *(const float4*)(bias + off);
    float4 v;
    v.x = acc.x * inv + bv.x;  v.x = v.x > 0.f ? v.x : expm1f(v.x);
    v.y = acc.y * inv + bv.y;  v.y = v.y > 0.f ? v.y : expm1f(v.y);
    v.z = acc.z * inv + bv.z;  v.z = v.z > 0.f ? v.z : expm1f(v.z);
    v.w = acc.w * inv + bv.w;  v.w = v.w > 0.f ? v.w : expm1f(v.w);
    *(float4*)(out + (size_t)n * (8 * CH) + off) = v;
}

// ---------------- pool + head (sorted batch -> no atomics) ------------------
__global__ void gstart_kernel(const int* __restrict__ batch, int* __restrict__ gstart) {
    int g = threadIdx.x;                 // one block of 256
    int lo = 0, hi = N_NODES;
    while (lo < hi) {                    // lower_bound(batch, g)
        int mid = (lo + hi) >> 1;
        if (batch[mid] < g) lo = mid + 1; else hi = mid;
    }
    gstart[g] = lo;
    if (g == 0) gstart[N_GRAPHS] = N_NODES;
}

// 512 threads: 4 node-strips x 128 features, LDS combine, then MLP head.
__global__ __launch_bounds__(512) void pool_head_kernel(
        const float* __restrict__ act, const int* __restrict__ gstart,
        const float* __restrict__ fc1_w, const float* __restrict__ fc1_b,
        const float* __restrict__ fc2_w, const float* __restrict__ fc2_b,
        float* __restrict__ out) {
    int g = blockIdx.x;
    int t = threadIdx.x;
    int f = t & 127, strip = t >> 7;       // 0..3
    int n0 = gstart[g], n1 = gstart[g + 1];
    float s = 0.f;
    for (int n = n0 + strip; n < n1; n += 4) s += act[(size_t)n * 128 + f];
    __shared__ float sm[4][128];
    __shared__ float zz[10];
    sm[strip][f] = s;
    __syncthreads();
    if (strip == 0) {
        float cnt = (float)(n1 - n0);
        cnt = cnt > 1.f ? cnt : 1.f;
        sm[0][f] = (sm[0][f] + sm[1][f] + sm[2][f] + sm[3][f]) / cnt;
    }
    __syncthreads();
    if (t < 10) {
        float z = fc1_b[t];
        for (int q = 0; q < 128; ++q) z += sm[0][q] * fc1_w[q * 10 + t];
        zz[t] = z > 0.f ? z : 0.f;
    }
    __syncthreads();
    if (t == 0) {
        float o = fc2_b[0];
#pragma unroll
        for (int j = 0; j < 10; ++j) o += zz[j] * fc2_w[j];
        out[g] = o;
    }
}

extern "C" void kernel_launch(void* const* d_in, const int* in_sizes, int n_in,
                              void* d_out, int out_size, void* d_ws, size_t ws_size,
                              hipStream_t stream) {
    const float* x      = (const float*)d_in[0];
    const float* W1     = (const float*)d_in[1];
    const float* a_src1 = (const float*)d_in[2];
    const float* a_dst1 = (const float*)d_in[3];
    const float* b1     = (const float*)d_in[4];
    const float* W2     = (const float*)d_in[5];
    const float* a_src2 = (const float*)d_in[6];
    const float* a_dst2 = (const float*)d_in[7];
    const float* b2     = (const float*)d_in[8];
    const float* W3     = (const float*)d_in[9];
    const float* a_src3 = (const float*)d_in[10];
    const float* a_dst3 = (const float*)d_in[11];
    const float* b3     = (const float*)d_in[12];
    const float* fc1_w  = (const float*)d_in[13];
    const float* fc1_b  = (const float*)d_in[14];
    const float* fc2_w  = (const float*)d_in[15];
    const float* fc2_b  = (const float*)d_in[16];
    const int*   eidx   = (const int*)d_in[17];
    const int*   batch  = (const int*)d_in[18];
    const int* esrc = eidx;
    const int* edst = eidx + N_EDGES;
    float* out = (float*)d_out;

    float* ws      = (float*)d_ws;
    float* h_buf   = ws;                         // 6,400,000 f32
    float* act0    = h_buf + 6400000;            // 6,400,000
    float* act1    = act0 + 6400000;             // 6,400,000
    float* asrcb   = act1 + 6400000;             // 400,000
    float* adstb   = asrcb + 400000;             // 400,000
    int*   cnt     = (int*)(adstb + 400000);     // 50,000
    int*   excl    = cnt + 50000;                // 50,000
    int*   bsum    = excl + 50000;               // 256
    int*   row_ptr = bsum + 256;                 // 50,001
    int*   cursor  = row_ptr + 50001;            // 50,000
    int*   edge_src= cursor + 50000;             // 850,000
    int*   gstart  = edge_src + 850000;          // 257

    const int B = 256;
    dim3 blk(B);
    dim3 g_gemm((N_NODES + 63) / 64);
    dim3 g_alpha((N_NODES * HEADS + B - 1) / B);
    dim3 g_edge((N_TOT + B - 1) / B);
    dim3 g_gather((N_NODES * 64 + B - 1) / B);
    const int nblk_scan = (N_NODES + 255) / 256;   // 196

    // ---- build CSR (once per call, reused by all 3 layers) ----
    hipMemsetAsync(cnt, 0, 50000 * 4, stream);
    hipMemsetAsync(cursor, 0, 50000 * 4, stream);
    hist_kernel<<<g_edge, blk, 0, stream>>>(edst, cnt);
    scan1_kernel<<<dim3(nblk_scan), blk, 0, stream>>>(cnt, excl, bsum);
    scan2_kernel<<<dim3(1), blk, 0, stream>>>(bsum, nblk_scan);
    scan3_kernel<<<dim3((N_NODES + B) / B), blk, 0, stream>>>(excl, bsum, row_ptr);
    scatter_kernel<<<g_edge, blk, 0, stream>>>(esrc, edst, row_ptr, cursor, edge_src);
    gstart_kernel<<<dim3(1), blk, 0, stream>>>(batch, gstart);

    // ---- Layer 1: Fin=32, F=64, CH=8 ----
    gemm_kernel<32, 64><<<g_gemm, blk, 0, stream>>>(x, W1, h_buf);
    alpha_kernel<8><<<g_alpha, blk, 0, stream>>>(h_buf, a_src1, a_dst1, asrcb, adstb);
    gat_gather_kernel<8><<<g_gather, blk, 0, stream>>>(row_ptr, edge_src, asrcb, adstb,
                                                       h_buf, b1, act0);

    // ---- Layer 2: Fin=64, F=128, CH=16 ----
    gemm_kernel<64, 128><<<g_gemm, blk, 0, stream>>>(act0, W2, h_buf);
    alpha_kernel<16><<<g_alpha, blk, 0, stream>>>(h_buf, a_src2, a_dst2, asrcb, adstb);
    gat_gather_kernel<16><<<g_gather, blk, 0, stream>>>(row_ptr, edge_src, asrcb, adstb,
                                                        h_buf, b2, act1);

    // ---- Layer 3: Fin=128, F=128, CH=16 ----
    gemm_kernel<128, 128><<<g_gemm, blk, 0, stream>>>(act1, W3, h_buf);
    alpha_kernel<16><<<g_alpha, blk, 0, stream>>>(h_buf, a_src3, a_dst3, asrcb, adstb);
    gat_gather_kernel<16><<<g_gather, blk, 0, stream>>>(row_ptr, edge_src, asrcb, adstb,
                                                        h_buf, b3, act0);

    // ---- Pool + head (no atomics) ----
    pool_head_kernel<<<dim3(N_GRAPHS), dim3(512), 0, stream>>>(act0, gstart, fc1_w, fc1_b,
                                                               fc2_w, fc2_b, out);
}

// Round 8
// 371.965 us; speedup vs baseline: 42.5864x; 1.0300x over previous
//
#include <hip/hip_runtime.h>
#include <hip/hip_bf16.h>

#define N_NODES   50000
#define N_EDGES   800000
#define N_TOT     850000   // edges + self loops
#define N_GRAPHS  256
#define HEADS     8
#define NEG_SLOPE 0.2f

// ---------------- dense GEMM: H[n][fout] = sum_k X[n][k]*W[k][fout] ----------
// 64-node tile, KC=32 k-chunks staged in LDS (X transposed), all b128 reads.
template<int FIN, int FOUT>
__global__ __launch_bounds__(256) void gemm_kernel(const float* __restrict__ X,
                                                   const float* __restrict__ W,
                                                   float* __restrict__ H) {
    constexpr int KC    = 32;
    constexpr int THR_F = FOUT / 4;        // threads spanning fout (32 or 16)
    constexpr int NPT   = 64 / (256 / THR_F); // nodes per thread (8 or 4)
    constexpr int XS_S  = 68;              // padded node-stride (16B aligned)
    __shared__ float xs[KC * XS_S];        // [k][node]
    __shared__ float ws[KC * FOUT];        // [k][fout]
    const int t = threadIdx.x;
    const int node0 = blockIdx.x * 64;
    const int fo  = (t % THR_F) * 4;
    const int ndb = (t / THR_F) * NPT;
    float4 acc[NPT];
#pragma unroll
    for (int i = 0; i < NPT; ++i) acc[i] = make_float4(0.f, 0.f, 0.f, 0.f);

    const int xn = t >> 2, ks = (t & 3) * 8;   // staging roles
    for (int kc = 0; kc < FIN; kc += KC) {
        __syncthreads();
        // stage X chunk transposed: xs[k][node]
        float4 a0 = make_float4(0.f,0.f,0.f,0.f), a1 = a0;
        if (node0 + xn < N_NODES) {
            const float* xp = X + (size_t)(node0 + xn) * FIN + kc + ks;
            a0 = *(const float4*)xp;
            a1 = *(const float4*)(xp + 4);
        }
        xs[(ks + 0) * XS_S + xn] = a0.x;
        xs[(ks + 1) * XS_S + xn] = a0.y;
        xs[(ks + 2) * XS_S + xn] = a0.z;
        xs[(ks + 3) * XS_S + xn] = a0.w;
        xs[(ks + 4) * XS_S + xn] = a1.x;
        xs[(ks + 5) * XS_S + xn] = a1.y;
        xs[(ks + 6) * XS_S + xn] = a1.z;
        xs[(ks + 7) * XS_S + xn] = a1.w;
        // stage W chunk (row-major, flat float4 copy)
        constexpr int WF4 = KC * FOUT / 4 / 256;   // float4 per thread (4 or 2)
        const float4* wsrc = (const float4*)(W + (size_t)kc * FOUT);
        float4* wdst = (float4*)ws;
#pragma unroll
        for (int i = 0; i < WF4; ++i) wdst[t * WF4 + i] = wsrc[t * WF4 + i];
        __syncthreads();
#pragma unroll 4
        for (int k = 0; k < KC; ++k) {
            float4 wv = *(const float4*)(ws + k * FOUT + fo);
#pragma unroll
            for (int q = 0; q < NPT / 4; ++q) {
                float4 xv = *(const float4*)(xs + k * XS_S + ndb + q * 4);
                acc[q*4+0].x += xv.x * wv.x; acc[q*4+0].y += xv.x * wv.y;
                acc[q*4+0].z += xv.x * wv.z; acc[q*4+0].w += xv.x * wv.w;
                acc[q*4+1].x += xv.y * wv.x; acc[q*4+1].y += xv.y * wv.y;
                acc[q*4+1].z += xv.y * wv.z; acc[q*4+1].w += xv.y * wv.w;
                acc[q*4+2].x += xv.z * wv.x; acc[q*4+2].y += xv.z * wv.y;
                acc[q*4+2].z += xv.z * wv.z; acc[q*4+2].w += xv.z * wv.w;
                acc[q*4+3].x += xv.w * wv.x; acc[q*4+3].y += xv.w * wv.y;
                acc[q*4+3].z += xv.w * wv.z; acc[q*4+3].w += xv.w * wv.w;
            }
        }
    }
#pragma unroll
    for (int i = 0; i < NPT; ++i) {
        int row = node0 + ndb + i;
        if (row < N_NODES) *(float4*)(H + (size_t)row * FOUT + fo) = acc[i];
    }
}

// --------- asrc[n][h] = sum_c H[n][h][c]*a_src[h][c]; same for adst ---------
template<int CH>
__global__ void alpha_kernel(const float* __restrict__ H,
                             const float* __restrict__ a_src,
                             const float* __restrict__ a_dst,
                             float* __restrict__ asrc, float* __restrict__ adst) {
    int tid = blockIdx.x * blockDim.x + threadIdx.x;
    if (tid >= N_NODES * HEADS) return;
    int n = tid / HEADS, h = tid % HEADS;
    const float4* hp = (const float4*)(H + (size_t)n * (HEADS * CH) + h * CH);
    const float4* as = (const float4*)(a_src + h * CH);
    const float4* ad = (const float4*)(a_dst + h * CH);
    float s = 0.f, d = 0.f;
#pragma unroll
    for (int c = 0; c < CH / 4; ++c) {
        float4 v = hp[c], a = as[c], b = ad[c];
        s += v.x * a.x + v.y * a.y + v.z * a.z + v.w * a.w;
        d += v.x * b.x + v.y * b.y + v.z * b.z + v.w * b.w;
    }
    asrc[tid] = s;
    adst[tid] = d;
}

// ---------------- CSR build (counting sort by dst) --------------------------
__global__ void hist_kernel(const int* __restrict__ edst, int* __restrict__ cnt) {
    int e = blockIdx.x * blockDim.x + threadIdx.x;
    if (e >= N_TOT) return;
    int d = (e < N_EDGES) ? edst[e] : e - N_EDGES;
    atomicAdd(&cnt[d], 1);
}

__global__ void scan1_kernel(const int* __restrict__ cnt, int* __restrict__ excl,
                             int* __restrict__ bsum) {
    __shared__ int sm[256];
    int t = threadIdx.x;
    int i = blockIdx.x * 256 + t;
    int v = (i < N_NODES) ? cnt[i] : 0;
    sm[t] = v;
    __syncthreads();
    for (int off = 1; off < 256; off <<= 1) {
        int x = (t >= off) ? sm[t - off] : 0;
        __syncthreads();
        sm[t] += x;
        __syncthreads();
    }
    if (i < N_NODES) excl[i] = sm[t] - v;
    if (t == 255) bsum[blockIdx.x] = sm[255];
}

__global__ void scan2_kernel(int* __restrict__ bsum, int nblk) {
    __shared__ int sm[256];
    int t = threadIdx.x;
    int v = (t < nblk) ? bsum[t] : 0;
    sm[t] = v;
    __syncthreads();
    for (int off = 1; off < 256; off <<= 1) {
        int x = (t >= off) ? sm[t - off] : 0;
        __syncthreads();
        sm[t] += x;
        __syncthreads();
    }
    if (t < nblk) bsum[t] = sm[t] - v;   // exclusive
}

__global__ void scan3_kernel(const int* __restrict__ excl, const int* __restrict__ bsum,
                             int* __restrict__ row_ptr) {
    int i = blockIdx.x * blockDim.x + threadIdx.x;
    if (i < N_NODES) row_ptr[i] = excl[i] + bsum[i >> 8];
    if (i == N_NODES) row_ptr[N_NODES] = N_TOT;
}

__global__ void scatter_kernel(const int* __restrict__ esrc, const int* __restrict__ edst,
                               const int* __restrict__ row_ptr, int* __restrict__ cursor,
                               int* __restrict__ edge_src) {
    int e = blockIdx.x * blockDim.x + threadIdx.x;
    if (e >= N_TOT) return;
    int s, d;
    if (e < N_EDGES) { s = esrc[e]; d = edst[e]; } else { s = d = e - N_EDGES; }
    int pos = row_ptr[d] + atomicAdd(&cursor[d], 1);
    edge_src[pos] = s;
}

// ------- fused gather: softmax (no max-shift; logits O(1), f32-safe) --------
// one wave per destination node; LPE = 2*CH lanes per edge (float4 over row),
// SPLIT = 64/LPE edge-chains; pair-unrolled -> 2*SPLIT outstanding gathers.
template<int CH>
__global__ __launch_bounds__(256) void gat_gather_kernel(
        const int* __restrict__ row_ptr, const int* __restrict__ edge_src,
        const float* __restrict__ asrc, const float* __restrict__ adst,
        const float* __restrict__ H, const float* __restrict__ bias,
        float* __restrict__ out) {
    constexpr int LPE   = 2 * CH;    // 32 (CH16) or 16 (CH8)
    constexpr int SPLIT = 64 / LPE;  // 2 or 4
    constexpr int LPH   = CH / 4;    // lanes per head (4 or 2)
    constexpr int HS    = 8 * CH;    // floats per row
    const int n = (blockIdx.x * blockDim.x + threadIdx.x) >> 6;
    if (n >= N_NODES) return;
    const int lane = threadIdx.x & 63;
    const int sub = lane / LPE;
    const int li  = lane & (LPE - 1);
    const int h   = li / LPH;
    const int off = h * CH + (li & (LPH - 1)) * 4;   // float offset in row
    const float adst_h = adst[n * 8 + h];
    const int e0 = row_ptr[n], e1 = row_ptr[n + 1];
    float sum = 0.f;
    float4 acc = make_float4(0.f, 0.f, 0.f, 0.f);
    int e = e0 + sub;
    // pair-unrolled main loop: 2 independent gather chains per sub-group
    for (; e + SPLIT < e1; e += 2 * SPLIT) {
        int s0 = edge_src[e];
        int s1 = edge_src[e + SPLIT];
        float l0 = asrc[s0 * 8 + h] + adst_h;
        float l1 = asrc[s1 * 8 + h] + adst_h;
        float4 h0 = *(const float4*)(H + (size_t)s0 * HS + off);
        float4 h1 = *(const float4*)(H + (size_t)s1 * HS + off);
        l0 = l0 > 0.f ? l0 : NEG_SLOPE * l0;
        l1 = l1 > 0.f ? l1 : NEG_SLOPE * l1;
        float w0 = __expf(l0), w1 = __expf(l1);
        sum += w0 + w1;
        acc.x += w0 * h0.x + w1 * h1.x;
        acc.y += w0 * h0.y + w1 * h1.y;
        acc.z += w0 * h0.z + w1 * h1.z;
        acc.w += w0 * h0.w + w1 * h1.w;
    }
    if (e < e1) {                       // tail (single edge)
        int s = edge_src[e];
        float l = asrc[s * 8 + h] + adst_h;
        float4 hv = *(const float4*)(H + (size_t)s * HS + off);
        l = l > 0.f ? l : NEG_SLOPE * l;
        float w = __expf(l);
        sum += w;
        acc.x += w * hv.x;
        acc.y += w * hv.y;
        acc.z += w * hv.z;
        acc.w += w * hv.w;
    }
    // merge SPLIT sub-accumulators (plain adds — same implicit shift of 0)
#pragma unroll
    for (int mask = LPE; mask < 64; mask <<= 1) {
        sum   += __shfl_xor(sum, mask, 64);
        acc.x += __shfl_xor(acc.x, mask, 64);
        acc.y += __shfl_xor(acc.y, mask, 64);
        acc.z += __shfl_xor(acc.z, mask, 64);
        acc.w += __shfl_xor(acc.w, mask, 64);
    }
    float inv = 1.0f / (sum + 1e-16f);
    float4 bv = *(const float4*)(bias + off);
    float4 v;
    v.x = acc.x * inv + bv.x;  v.x = v.x > 0.f ? v.x : expm1f(v.x);
    v.y = acc.y * inv + bv.y;  v.y = v.y > 0.f ? v.y : expm1f(v.y);
    v.z = acc.z * inv + bv.z;  v.z = v.z > 0.f ? v.z : expm1f(v.z);
    v.w = acc.w * inv + bv.w;  v.w = v.w > 0.f ? v.w : expm1f(v.w);
    *(float4*)(out + (size_t)n * HS + off) = v;
}

// ---------------- pool + head (sorted batch -> no atomics) ------------------
__global__ void gstart_kernel(const int* __restrict__ batch, int* __restrict__ gstart) {
    int g = threadIdx.x;                 // one block of 256
    int lo = 0, hi = N_NODES;
    while (lo < hi) {                    // lower_bound(batch, g)
        int mid = (lo + hi) >> 1;
        if (batch[mid] < g) lo = mid + 1; else hi = mid;
    }
    gstart[g] = lo;
    if (g == 0) gstart[N_GRAPHS] = N_NODES;
}

// 512 threads: 4 node-strips x 128 features, LDS combine, then MLP head.
__global__ __launch_bounds__(512) void pool_head_kernel(
        const float* __restrict__ act, const int* __restrict__ gstart,
        const float* __restrict__ fc1_w, const float* __restrict__ fc1_b,
        const float* __restrict__ fc2_w, const float* __restrict__ fc2_b,
        float* __restrict__ out) {
    int g = blockIdx.x;
    int t = threadIdx.x;
    int f = t & 127, strip = t >> 7;       // 0..3
    int n0 = gstart[g], n1 = gstart[g + 1];
    float s = 0.f;
    for (int n = n0 + strip; n < n1; n += 4) s += act[(size_t)n * 128 + f];
    __shared__ float sm[4][128];
    __shared__ float zz[10];
    sm[strip][f] = s;
    __syncthreads();
    if (strip == 0) {
        float cnt = (float)(n1 - n0);
        cnt = cnt > 1.f ? cnt : 1.f;
        sm[0][f] = (sm[0][f] + sm[1][f] + sm[2][f] + sm[3][f]) / cnt;
    }
    __syncthreads();
    if (t < 10) {
        float z = fc1_b[t];
        for (int q = 0; q < 128; ++q) z += sm[0][q] * fc1_w[q * 10 + t];
        zz[t] = z > 0.f ? z : 0.f;
    }
    __syncthreads();
    if (t == 0) {
        float o = fc2_b[0];
#pragma unroll
        for (int j = 0; j < 10; ++j) o += zz[j] * fc2_w[j];
        out[g] = o;
    }
}

extern "C" void kernel_launch(void* const* d_in, const int* in_sizes, int n_in,
                              void* d_out, int out_size, void* d_ws, size_t ws_size,
                              hipStream_t stream) {
    const float* x      = (const float*)d_in[0];
    const float* W1     = (const float*)d_in[1];
    const float* a_src1 = (const float*)d_in[2];
    const float* a_dst1 = (const float*)d_in[3];
    const float* b1     = (const float*)d_in[4];
    const float* W2     = (const float*)d_in[5];
    const float* a_src2 = (const float*)d_in[6];
    const float* a_dst2 = (const float*)d_in[7];
    const float* b2     = (const float*)d_in[8];
    const float* W3     = (const float*)d_in[9];
    const float* a_src3 = (const float*)d_in[10];
    const float* a_dst3 = (const float*)d_in[11];
    const float* b3     = (const float*)d_in[12];
    const float* fc1_w  = (const float*)d_in[13];
    const float* fc1_b  = (const float*)d_in[14];
    const float* fc2_w  = (const float*)d_in[15];
    const float* fc2_b  = (const float*)d_in[16];
    const int*   eidx   = (const int*)d_in[17];
    const int*   batch  = (const int*)d_in[18];
    const int* esrc = eidx;
    const int* edst = eidx + N_EDGES;
    float* out = (float*)d_out;

    float* ws      = (float*)d_ws;
    float* h_buf   = ws;                         // 6,400,000 f32
    float* act0    = h_buf + 6400000;            // 6,400,000
    float* act1    = act0 + 6400000;             // 6,400,000
    float* asrcb   = act1 + 6400000;             // 400,000
    float* adstb   = asrcb + 400000;             // 400,000
    int*   cnt     = (int*)(adstb + 400000);     // 50,000
    int*   excl    = cnt + 50000;                // 50,000
    int*   bsum    = excl + 50000;               // 256
    int*   row_ptr = bsum + 256;                 // 50,001
    int*   cursor  = row_ptr + 50001;            // 50,000
    int*   edge_src= cursor + 50000;             // 850,000
    int*   gstart  = edge_src + 850000;          // 257

    const int B = 256;
    dim3 blk(B);
    dim3 g_gemm((N_NODES + 63) / 64);
    dim3 g_alpha((N_NODES * HEADS + B - 1) / B);
    dim3 g_edge((N_TOT + B - 1) / B);
    dim3 g_gather((N_NODES * 64 + B - 1) / B);
    const int nblk_scan = (N_NODES + 255) / 256;   // 196

    // ---- build CSR (once per call, reused by all 3 layers) ----
    hipMemsetAsync(cnt, 0, 50000 * 4, stream);
    hipMemsetAsync(cursor, 0, 50000 * 4, stream);
    hist_kernel<<<g_edge, blk, 0, stream>>>(edst, cnt);
    scan1_kernel<<<dim3(nblk_scan), blk, 0, stream>>>(cnt, excl, bsum);
    scan2_kernel<<<dim3(1), blk, 0, stream>>>(bsum, nblk_scan);
    scan3_kernel<<<dim3((N_NODES + B) / B), blk, 0, stream>>>(excl, bsum, row_ptr);
    scatter_kernel<<<g_edge, blk, 0, stream>>>(esrc, edst, row_ptr, cursor, edge_src);
    gstart_kernel<<<dim3(1), blk, 0, stream>>>(batch, gstart);

    // ---- Layer 1: Fin=32, F=64, CH=8 ----
    gemm_kernel<32, 64><<<g_gemm, blk, 0, stream>>>(x, W1, h_buf);
    alpha_kernel<8><<<g_alpha, blk, 0, stream>>>(h_buf, a_src1, a_dst1, asrcb, adstb);
    gat_gather_kernel<8><<<g_gather, blk, 0, stream>>>(row_ptr, edge_src, asrcb, adstb,
                                                       h_buf, b1, act0);

    // ---- Layer 2: Fin=64, F=128, CH=16 ----
    gemm_kernel<64, 128><<<g_gemm, blk, 0, stream>>>(act0, W2, h_buf);
    alpha_kernel<16><<<g_alpha, blk, 0, stream>>>(h_buf, a_src2, a_dst2, asrcb, adstb);
    gat_gather_kernel<16><<<g_gather, blk, 0, stream>>>(row_ptr, edge_src, asrcb, adstb,
                                                        h_buf, b2, act1);

    // ---- Layer 3: Fin=128, F=128, CH=16 ----
    gemm_kernel<128, 128><<<g_gemm, blk, 0, stream>>>(act1, W3, h_buf);
    alpha_kernel<16><<<g_alpha, blk, 0, stream>>>(h_buf, a_src3, a_dst3, asrcb, adstb);
    gat_gather_kernel<16><<<g_gather, blk, 0, stream>>>(row_ptr, edge_src, asrcb, adstb,
                                                        h_buf, b3, act0);

    // ---- Pool + head (no atomics) ----
    pool_head_kernel<<<dim3(N_GRAPHS), dim3(512), 0, stream>>>(act0, gstart, fc1_w, fc1_b,
                                                               fc2_w, fc2_b, out);
}

// Round 9
// 349.131 us; speedup vs baseline: 45.3717x; 1.0654x over previous
//
#include <hip/hip_runtime.h>
#include <hip/hip_bf16.h>

#define N_NODES   50000
#define N_EDGES   800000
#define N_TOT     850000   // edges + self loops
#define N_GRAPHS  256
#define HEADS     8
#define NEG_SLOPE 0.2f

// ------- dense GEMM + fused alpha: H = X@W; asrc/adst = <H, a_src/a_dst> ----
// 64-node tile, KC=32 k-chunks staged in LDS (X transposed), all b128 reads.
template<int FIN, int FOUT>
__global__ __launch_bounds__(256) void gemm_kernel(const float* __restrict__ X,
                                                   const float* __restrict__ W,
                                                   float* __restrict__ H,
                                                   const float* __restrict__ a_src,
                                                   const float* __restrict__ a_dst,
                                                   float* __restrict__ asrc_o,
                                                   float* __restrict__ adst_o) {
    constexpr int KC    = 32;
    constexpr int THR_F = FOUT / 4;        // threads spanning fout (32 or 16)
    constexpr int NPT   = 64 / (256 / THR_F); // nodes per thread (8 or 4)
    constexpr int XS_S  = 68;              // padded node-stride (16B aligned)
    constexpr int CH    = FOUT / 8;        // channels per head
    __shared__ float xs[KC * XS_S];        // [k][node]
    __shared__ float ws[KC * FOUT];        // [k][fout]
    const int t = threadIdx.x;
    const int node0 = blockIdx.x * 64;
    const int fo  = (t % THR_F) * 4;
    const int ndb = (t / THR_F) * NPT;
    float4 acc[NPT];
#pragma unroll
    for (int i = 0; i < NPT; ++i) acc[i] = make_float4(0.f, 0.f, 0.f, 0.f);

    const int xn = t >> 2, ks = (t & 3) * 8;   // staging roles
    for (int kc = 0; kc < FIN; kc += KC) {
        __syncthreads();
        // stage X chunk transposed: xs[k][node]
        float4 a0 = make_float4(0.f,0.f,0.f,0.f), a1 = a0;
        if (node0 + xn < N_NODES) {
            const float* xp = X + (size_t)(node0 + xn) * FIN + kc + ks;
            a0 = *(const float4*)xp;
            a1 = *(const float4*)(xp + 4);
        }
        xs[(ks + 0) * XS_S + xn] = a0.x;
        xs[(ks + 1) * XS_S + xn] = a0.y;
        xs[(ks + 2) * XS_S + xn] = a0.z;
        xs[(ks + 3) * XS_S + xn] = a0.w;
        xs[(ks + 4) * XS_S + xn] = a1.x;
        xs[(ks + 5) * XS_S + xn] = a1.y;
        xs[(ks + 6) * XS_S + xn] = a1.z;
        xs[(ks + 7) * XS_S + xn] = a1.w;
        // stage W chunk (row-major, flat float4 copy)
        constexpr int WF4 = KC * FOUT / 4 / 256;   // float4 per thread (4 or 2)
        const float4* wsrc = (const float4*)(W + (size_t)kc * FOUT);
        float4* wdst = (float4*)ws;
#pragma unroll
        for (int i = 0; i < WF4; ++i) wdst[t * WF4 + i] = wsrc[t * WF4 + i];
        __syncthreads();
#pragma unroll 4
        for (int k = 0; k < KC; ++k) {
            float4 wv = *(const float4*)(ws + k * FOUT + fo);
#pragma unroll
            for (int q = 0; q < NPT / 4; ++q) {
                float4 xv = *(const float4*)(xs + k * XS_S + ndb + q * 4);
                acc[q*4+0].x += xv.x * wv.x; acc[q*4+0].y += xv.x * wv.y;
                acc[q*4+0].z += xv.x * wv.z; acc[q*4+0].w += xv.x * wv.w;
                acc[q*4+1].x += xv.y * wv.x; acc[q*4+1].y += xv.y * wv.y;
                acc[q*4+1].z += xv.y * wv.z; acc[q*4+1].w += xv.y * wv.w;
                acc[q*4+2].x += xv.z * wv.x; acc[q*4+2].y += xv.z * wv.y;
                acc[q*4+2].z += xv.z * wv.z; acc[q*4+2].w += xv.z * wv.w;
                acc[q*4+3].x += xv.w * wv.x; acc[q*4+3].y += xv.w * wv.y;
                acc[q*4+3].z += xv.w * wv.z; acc[q*4+3].w += xv.w * wv.w;
            }
        }
    }
    const int h   = fo / CH;           // head owning this thread's 4 channels
    const float4 asv = *(const float4*)(a_src + h * CH + (fo % CH));
    const float4 adv = *(const float4*)(a_dst + h * CH + (fo % CH));
    constexpr int LPH = CH / 4;        // threads per head (4 or 2)
#pragma unroll
    for (int i = 0; i < NPT; ++i) {
        int row = node0 + ndb + i;
        if (row < N_NODES) *(float4*)(H + (size_t)row * FOUT + fo) = acc[i];
        float s = acc[i].x*asv.x + acc[i].y*asv.y + acc[i].z*asv.z + acc[i].w*asv.w;
        float d = acc[i].x*adv.x + acc[i].y*adv.y + acc[i].z*adv.z + acc[i].w*adv.w;
        s += __shfl_xor(s, 1, 64);
        d += __shfl_xor(d, 1, 64);
        if (LPH == 4) { s += __shfl_xor(s, 2, 64); d += __shfl_xor(d, 2, 64); }
        if ((t & (LPH - 1)) == 0 && row < N_NODES) {
            asrc_o[row * 8 + h] = s;
            adst_o[row * 8 + h] = d;
        }
    }
}

// ---------------- CSR build (counting sort by dst) --------------------------
__global__ void hist_kernel(const int* __restrict__ edst, int* __restrict__ cnt) {
    int e = blockIdx.x * blockDim.x + threadIdx.x;
    if (e >= N_TOT) return;
    int d = (e < N_EDGES) ? edst[e] : e - N_EDGES;
    atomicAdd(&cnt[d], 1);
}

__global__ void scan1_kernel(const int* __restrict__ cnt, int* __restrict__ excl,
                             int* __restrict__ bsum) {
    __shared__ int sm[256];
    int t = threadIdx.x;
    int i = blockIdx.x * 256 + t;
    int v = (i < N_NODES) ? cnt[i] : 0;
    sm[t] = v;
    __syncthreads();
    for (int off = 1; off < 256; off <<= 1) {
        int x = (t >= off) ? sm[t - off] : 0;
        __syncthreads();
        sm[t] += x;
        __syncthreads();
    }
    if (i < N_NODES) excl[i] = sm[t] - v;
    if (t == 255) bsum[blockIdx.x] = sm[255];
}

__global__ void scan2_kernel(int* __restrict__ bsum, int nblk) {
    __shared__ int sm[256];
    int t = threadIdx.x;
    int v = (t < nblk) ? bsum[t] : 0;
    sm[t] = v;
    __syncthreads();
    for (int off = 1; off < 256; off <<= 1) {
        int x = (t >= off) ? sm[t - off] : 0;
        __syncthreads();
        sm[t] += x;
        __syncthreads();
    }
    if (t < nblk) bsum[t] = sm[t] - v;   // exclusive
}

__global__ void scan3_kernel(const int* __restrict__ excl, const int* __restrict__ bsum,
                             int* __restrict__ row_ptr) {
    int i = blockIdx.x * blockDim.x + threadIdx.x;
    if (i < N_NODES) row_ptr[i] = excl[i] + bsum[i >> 8];
    if (i == N_NODES) row_ptr[N_NODES] = N_TOT;
}

__global__ void scatter_kernel(const int* __restrict__ esrc, const int* __restrict__ edst,
                               const int* __restrict__ row_ptr, int* __restrict__ cursor,
                               int* __restrict__ edge_src) {
    int e = blockIdx.x * blockDim.x + threadIdx.x;
    if (e >= N_TOT) return;
    int s, d;
    if (e < N_EDGES) { s = esrc[e]; d = edst[e]; } else { s = d = e - N_EDGES; }
    int pos = row_ptr[d] + atomicAdd(&cursor[d], 1);
    edge_src[pos] = s;
}

// ------- fused gather: softmax (no max-shift; logits O(1), f32-safe) --------
// one wave per destination node; LPE = 2*CH lanes per edge (float4 over row),
// SPLIT = 64/LPE edge-chains; 4x unrolled -> 4*SPLIT outstanding gathers.
template<int CH>
__global__ __launch_bounds__(256) void gat_gather_kernel(
        const int* __restrict__ row_ptr, const int* __restrict__ edge_src,
        const float* __restrict__ asrc, const float* __restrict__ adst,
        const float* __restrict__ H, const float* __restrict__ bias,
        float* __restrict__ out) {
    constexpr int LPE   = 2 * CH;    // 32 (CH16) or 16 (CH8)
    constexpr int SPLIT = 64 / LPE;  // 2 or 4
    constexpr int LPH   = CH / 4;    // lanes per head (4 or 2)
    constexpr int HS    = 8 * CH;    // floats per row
    const int n = (blockIdx.x * blockDim.x + threadIdx.x) >> 6;
    if (n >= N_NODES) return;
    const int lane = threadIdx.x & 63;
    const int sub = lane / LPE;
    const int li  = lane & (LPE - 1);
    const int h   = li / LPH;
    const int off = h * CH + (li & (LPH - 1)) * 4;   // float offset in row
    const float adst_h = adst[n * 8 + h];
    const int e0 = row_ptr[n], e1 = row_ptr[n + 1];
    float sum = 0.f;
    float4 acc = make_float4(0.f, 0.f, 0.f, 0.f);
    int e = e0 + sub;
    // 4-way unrolled main loop: 4 independent gather chains per sub-group
    for (; e + 3 * SPLIT < e1; e += 4 * SPLIT) {
        int s0 = edge_src[e];
        int s1 = edge_src[e + SPLIT];
        int s2 = edge_src[e + 2 * SPLIT];
        int s3 = edge_src[e + 3 * SPLIT];
        float l0 = asrc[s0 * 8 + h] + adst_h;
        float l1 = asrc[s1 * 8 + h] + adst_h;
        float l2 = asrc[s2 * 8 + h] + adst_h;
        float l3 = asrc[s3 * 8 + h] + adst_h;
        float4 h0 = *(const float4*)(H + (size_t)s0 * HS + off);
        float4 h1 = *(const float4*)(H + (size_t)s1 * HS + off);
        float4 h2 = *(const float4*)(H + (size_t)s2 * HS + off);
        float4 h3 = *(const float4*)(H + (size_t)s3 * HS + off);
        l0 = l0 > 0.f ? l0 : NEG_SLOPE * l0;
        l1 = l1 > 0.f ? l1 : NEG_SLOPE * l1;
        l2 = l2 > 0.f ? l2 : NEG_SLOPE * l2;
        l3 = l3 > 0.f ? l3 : NEG_SLOPE * l3;
        float w0 = __expf(l0), w1 = __expf(l1), w2 = __expf(l2), w3 = __expf(l3);
        sum += (w0 + w1) + (w2 + w3);
        acc.x += w0 * h0.x + w1 * h1.x + w2 * h2.x + w3 * h3.x;
        acc.y += w0 * h0.y + w1 * h1.y + w2 * h2.y + w3 * h3.y;
        acc.z += w0 * h0.z + w1 * h1.z + w2 * h2.z + w3 * h3.z;
        acc.w += w0 * h0.w + w1 * h1.w + w2 * h2.w + w3 * h3.w;
    }
    for (; e < e1; e += SPLIT) {        // tail (strided singles, <=3)
        int s = edge_src[e];
        float l = asrc[s * 8 + h] + adst_h;
        float4 hv = *(const float4*)(H + (size_t)s * HS + off);
        l = l > 0.f ? l : NEG_SLOPE * l;
        float w = __expf(l);
        sum += w;
        acc.x += w * hv.x;
        acc.y += w * hv.y;
        acc.z += w * hv.z;
        acc.w += w * hv.w;
    }
    // merge SPLIT sub-accumulators (plain adds — same implicit shift of 0)
#pragma unroll
    for (int mask = LPE; mask < 64; mask <<= 1) {
        sum   += __shfl_xor(sum, mask, 64);
        acc.x += __shfl_xor(acc.x, mask, 64);
        acc.y += __shfl_xor(acc.y, mask, 64);
        acc.z += __shfl_xor(acc.z, mask, 64);
        acc.w += __shfl_xor(acc.w, mask, 64);
    }
    float inv = 1.0f / (sum + 1e-16f);
    float4 bv = *(const float4*)(bias + off);
    float4 v;
    v.x = acc.x * inv + bv.x;  v.x = v.x > 0.f ? v.x : expm1f(v.x);
    v.y = acc.y * inv + bv.y;  v.y = v.y > 0.f ? v.y : expm1f(v.y);
    v.z = acc.z * inv + bv.z;  v.z = v.z > 0.f ? v.z : expm1f(v.z);
    v.w = acc.w * inv + bv.w;  v.w = v.w > 0.f ? v.w : expm1f(v.w);
    *(float4*)(out + (size_t)n * HS + off) = v;
}

// ---------------- pool + head (sorted batch -> no atomics) ------------------
__global__ void gstart_kernel(const int* __restrict__ batch, int* __restrict__ gstart) {
    int g = threadIdx.x;                 // one block of 256
    int lo = 0, hi = N_NODES;
    while (lo < hi) {                    // lower_bound(batch, g)
        int mid = (lo + hi) >> 1;
        if (batch[mid] < g) lo = mid + 1; else hi = mid;
    }
    gstart[g] = lo;
    if (g == 0) gstart[N_GRAPHS] = N_NODES;
}

// 512 threads: 4 node-strips x 128 features, LDS combine, then MLP head.
__global__ __launch_bounds__(512) void pool_head_kernel(
        const float* __restrict__ act, const int* __restrict__ gstart,
        const float* __restrict__ fc1_w, const float* __restrict__ fc1_b,
        const float* __restrict__ fc2_w, const float* __restrict__ fc2_b,
        float* __restrict__ out) {
    int g = blockIdx.x;
    int t = threadIdx.x;
    int f = t & 127, strip = t >> 7;       // 0..3
    int n0 = gstart[g], n1 = gstart[g + 1];
    float s = 0.f;
    for (int n = n0 + strip; n < n1; n += 4) s += act[(size_t)n * 128 + f];
    __shared__ float sm[4][128];
    __shared__ float zz[10];
    sm[strip][f] = s;
    __syncthreads();
    if (strip == 0) {
        float cnt = (float)(n1 - n0);
        cnt = cnt > 1.f ? cnt : 1.f;
        sm[0][f] = (sm[0][f] + sm[1][f] + sm[2][f] + sm[3][f]) / cnt;
    }
    __syncthreads();
    if (t < 10) {
        float z = fc1_b[t];
        for (int q = 0; q < 128; ++q) z += sm[0][q] * fc1_w[q * 10 + t];
        zz[t] = z > 0.f ? z : 0.f;
    }
    __syncthreads();
    if (t == 0) {
        float o = fc2_b[0];
#pragma unroll
        for (int j = 0; j < 10; ++j) o += zz[j] * fc2_w[j];
        out[g] = o;
    }
}

extern "C" void kernel_launch(void* const* d_in, const int* in_sizes, int n_in,
                              void* d_out, int out_size, void* d_ws, size_t ws_size,
                              hipStream_t stream) {
    const float* x      = (const float*)d_in[0];
    const float* W1     = (const float*)d_in[1];
    const float* a_src1 = (const float*)d_in[2];
    const float* a_dst1 = (const float*)d_in[3];
    const float* b1     = (const float*)d_in[4];
    const float* W2     = (const float*)d_in[5];
    const float* a_src2 = (const float*)d_in[6];
    const float* a_dst2 = (const float*)d_in[7];
    const float* b2     = (const float*)d_in[8];
    const float* W3     = (const float*)d_in[9];
    const float* a_src3 = (const float*)d_in[10];
    const float* a_dst3 = (const float*)d_in[11];
    const float* b3     = (const float*)d_in[12];
    const float* fc1_w  = (const float*)d_in[13];
    const float* fc1_b  = (const float*)d_in[14];
    const float* fc2_w  = (const float*)d_in[15];
    const float* fc2_b  = (const float*)d_in[16];
    const int*   eidx   = (const int*)d_in[17];
    const int*   batch  = (const int*)d_in[18];
    const int* esrc = eidx;
    const int* edst = eidx + N_EDGES;
    float* out = (float*)d_out;

    float* ws      = (float*)d_ws;
    float* h_buf   = ws;                         // 6,400,000 f32
    float* act0    = h_buf + 6400000;            // 6,400,000
    float* act1    = act0 + 6400000;             // 6,400,000
    float* asrcb   = act1 + 6400000;             // 400,000
    float* adstb   = asrcb + 400000;             // 400,000
    int*   cnt     = (int*)(adstb + 400000);     // 50,000
    int*   cursor  = cnt + 50000;                // 50,000 (adjacent: one memset)
    int*   excl    = cursor + 50000;             // 50,000
    int*   bsum    = excl + 50000;               // 256
    int*   row_ptr = bsum + 256;                 // 50,001
    int*   edge_src= row_ptr + 50001;            // 850,000
    int*   gstart  = edge_src + 850000;          // 257

    const int B = 256;
    dim3 blk(B);
    dim3 g_gemm((N_NODES + 63) / 64);
    dim3 g_edge((N_TOT + B - 1) / B);
    dim3 g_gather((N_NODES * 64 + B - 1) / B);
    const int nblk_scan = (N_NODES + 255) / 256;   // 196

    // ---- build CSR (once per call, reused by all 3 layers) ----
    hipMemsetAsync(cnt, 0, 100000 * 4, stream);   // cnt + cursor
    hist_kernel<<<g_edge, blk, 0, stream>>>(edst, cnt);
    scan1_kernel<<<dim3(nblk_scan), blk, 0, stream>>>(cnt, excl, bsum);
    scan2_kernel<<<dim3(1), blk, 0, stream>>>(bsum, nblk_scan);
    scan3_kernel<<<dim3((N_NODES + B) / B), blk, 0, stream>>>(excl, bsum, row_ptr);
    scatter_kernel<<<g_edge, blk, 0, stream>>>(esrc, edst, row_ptr, cursor, edge_src);
    gstart_kernel<<<dim3(1), blk, 0, stream>>>(batch, gstart);

    // ---- Layer 1: Fin=32, F=64, CH=8 ----
    gemm_kernel<32, 64><<<g_gemm, blk, 0, stream>>>(x, W1, h_buf, a_src1, a_dst1,
                                                    asrcb, adstb);
    gat_gather_kernel<8><<<g_gather, blk, 0, stream>>>(row_ptr, edge_src, asrcb, adstb,
                                                       h_buf, b1, act0);

    // ---- Layer 2: Fin=64, F=128, CH=16 ----
    gemm_kernel<64, 128><<<g_gemm, blk, 0, stream>>>(act0, W2, h_buf, a_src2, a_dst2,
                                                     asrcb, adstb);
    gat_gather_kernel<16><<<g_gather, blk, 0, stream>>>(row_ptr, edge_src, asrcb, adstb,
                                                        h_buf, b2, act1);

    // ---- Layer 3: Fin=128, F=128, CH=16 ----
    gemm_kernel<128, 128><<<g_gemm, blk, 0, stream>>>(act1, W3, h_buf, a_src3, a_dst3,
                                                      asrcb, adstb);
    gat_gather_kernel<16><<<g_gather, blk, 0, stream>>>(row_ptr, edge_src, asrcb, adstb,
                                                        h_buf, b3, act0);

    // ---- Pool + head (no atomics) ----
    pool_head_kernel<<<dim3(N_GRAPHS), dim3(512), 0, stream>>>(act0, gstart, fc1_w, fc1_b,
                                                               fc2_w, fc2_b, out);
}